// Round 14
// baseline (251.415 us; speedup 1.0000x reference)
//
#include <hip/hip_runtime.h>

typedef unsigned short u16;
typedef short bf16x8 __attribute__((ext_vector_type(8)));   // 8 bf16 = 4 VGPR
typedef float floatx4 __attribute__((ext_vector_type(4)));

#define LSEQ 2048
#define BB 8
#define NTOK (LSEQ*BB)        // 16384 tokens, n = l*B + b
#define DMODEL 256
#define DINNER 512
#define NSEG 128
#define SEGLEN 16             // LSEQ / NSEG

__device__ __forceinline__ float siluf(float x){ return x / (1.f + __expf(-x)); }
__device__ __forceinline__ float b2f(u16 x){ return __uint_as_float(((unsigned)x) << 16); }
__device__ __forceinline__ u16 f2b(float f){
  unsigned u = __float_as_uint(f);
  unsigned r = (u + 0x7fffu + ((u >> 16) & 1u)) >> 16;
  return (u16)r;
}

// ---------------- prep: 5 weight transpose/casts, range-switched
// blocks: [0,128) WTe | [128,1152) WTi | [1152,1664) WTo | [1664,1760) WxT | [1760,1792) WhT
__global__ __launch_bounds__(256) void prep_k(
    const float* __restrict__ Wemb, const float* __restrict__ Win,
    const float* __restrict__ Wout, const float* __restrict__ Wx,
    const float* __restrict__ Wh,
    u16* __restrict__ WTe, u16* __restrict__ WTi, u16* __restrict__ WTo,
    u16* __restrict__ WxT, u16* __restrict__ WhT)
{
  int g = blockIdx.x, tid = threadIdx.x;
  if (g < 128) {                        // WTe[n][k], n<256, k<128
    int idx = g*256 + tid; int n = idx >> 7, k = idx & 127;
    WTe[idx] = f2b(Wemb[(size_t)k*256 + n]);
  } else if (g < 1152) {                // WTi[n][k], n<1024, k<256
    int idx = (g-128)*256 + tid; int n = idx >> 8, k = idx & 255;
    WTi[idx] = f2b(Win[(size_t)k*1024 + n]);
  } else if (g < 1664) {                // WTo[n][k], n<256, k<512
    int idx = (g-1152)*256 + tid; int n = idx >> 9, k = idx & 511;
    WTo[idx] = f2b(Wout[(size_t)k*256 + n]);
  } else if (g < 1760) {                // WxT[48][512]
    int idx = (g-1664)*256 + tid; int n = idx >> 9, k = idx & 511;
    WxT[idx] = f2b(Wx[(size_t)k*48 + n]);
  } else {                              // WhT[32][256]
    int idx = (g-1760)*256 + tid; int j = idx >> 8, k = idx & 255;
    WhT[idx] = f2b(Wh[(size_t)k*32 + j]);
  }
}

// ---------------- fused emb GEMM + RMSNorm: block = 64 tokens x full N=256.
__global__ __launch_bounds__(256) void embnorm_k(
    const float* __restrict__ s, const u16* __restrict__ WTe,
    const float* __restrict__ bemb, const float* __restrict__ nw,
    u16* __restrict__ Xb, u16* __restrict__ XNb)
{
  __shared__ u16 SH[64*264];            // staging As[64][40]+Bs[256][40]; epilogue Xs[64][264]
  __shared__ float ssq[64*4];
  __shared__ float rr[64];
  u16* As = SH;
  u16* Bs = SH + 64*40;
  const int tid = threadIdx.x;
  const int wave = tid >> 6, lane = tid & 63;
  const int quad = lane >> 4, l16 = lane & 15;
  const int m0 = blockIdx.x*64;
  const int wn = wave*64;
  const int srow = tid >> 2, sch = (tid & 3)*8;
  floatx4 acc[4][4];
  #pragma unroll
  for (int r = 0; r < 4; ++r)
    #pragma unroll
    for (int c = 0; c < 4; ++c) acc[r][c] = (floatx4){0.f,0.f,0.f,0.f};

  for (int k0 = 0; k0 < 128; k0 += 32) {
    {
      float4 v0 = *(const float4*)&s[(size_t)(m0+srow)*128 + k0 + sch];
      float4 v1 = *(const float4*)&s[(size_t)(m0+srow)*128 + k0 + sch + 4];
      __align__(16) u16 o[8];
      o[0]=f2b(v0.x); o[1]=f2b(v0.y); o[2]=f2b(v0.z); o[3]=f2b(v0.w);
      o[4]=f2b(v1.x); o[5]=f2b(v1.y); o[6]=f2b(v1.z); o[7]=f2b(v1.w);
      *(uint4*)&As[srow*40 + sch] = *(const uint4*)o;
    }
    #pragma unroll
    for (int p = 0; p < 4; ++p) {
      int row = srow + p*64;
      *(uint4*)&Bs[row*40 + sch] = *(const uint4*)&WTe[(size_t)row*128 + k0 + sch];
    }
    __syncthreads();
    bf16x8 af[4], bf[4];
    #pragma unroll
    for (int r = 0; r < 4; ++r) af[r] = *(const bf16x8*)&As[(r*16 + l16)*40 + quad*8];
    #pragma unroll
    for (int c = 0; c < 4; ++c) bf[c] = *(const bf16x8*)&Bs[(wn + c*16 + l16)*40 + quad*8];
    #pragma unroll
    for (int r = 0; r < 4; ++r)
      #pragma unroll
      for (int c = 0; c < 4; ++c)
        acc[r][c] = __builtin_amdgcn_mfma_f32_16x16x32_bf16(af[r], bf[c], acc[r][c], 0, 0, 0);
    __syncthreads();
  }
  u16* Xs = SH;                         // [64][264]
  #pragma unroll
  for (int c = 0; c < 4; ++c) {
    int n = wn + c*16 + l16;
    float bv = bemb[n];
    #pragma unroll
    for (int r = 0; r < 4; ++r)
      #pragma unroll
      for (int reg = 0; reg < 4; ++reg) {
        int ml = r*16 + quad*4 + reg;
        Xs[ml*264 + n] = f2b(acc[r][c][reg] + bv);
      }
  }
  __syncthreads();
  #pragma unroll
  for (int p = 0; p < 8; ++p) {
    int row = p*8 + (tid >> 5);
    int col = (tid & 31)*8;
    *(uint4*)&Xb[(size_t)(m0+row)*256 + col] = *(const uint4*)&Xs[row*264 + col];
  }
  const int tk = tid >> 2, q = tid & 3;
  float ss = 0.f;
  #pragma unroll
  for (int j = 0; j < 8; ++j) {
    uint4 v = *(const uint4*)&Xs[tk*264 + q*64 + j*8];
    const u16* u = (const u16*)&v;
    #pragma unroll
    for (int i = 0; i < 8; ++i) { float x = b2f(u[i]); ss += x*x; }
  }
  ssq[tk*4 + q] = ss;
  __syncthreads();
  if (q == 0)
    rr[tk] = rsqrtf((ssq[tk*4]+ssq[tk*4+1]+ssq[tk*4+2]+ssq[tk*4+3])*(1.f/DMODEL) + 1e-5f);
  __syncthreads();
  float r = rr[tk];
  #pragma unroll
  for (int j = 0; j < 8; ++j) {
    int idx = q*64 + j*8;
    uint4 v = *(const uint4*)&Xs[tk*264 + idx];
    const u16* u = (const u16*)&v;
    float4 w0 = *(const float4*)&nw[idx];
    float4 w1 = *(const float4*)&nw[idx+4];
    __align__(16) u16 o[8];
    o[0]=f2b(b2f(u[0])*r*w0.x); o[1]=f2b(b2f(u[1])*r*w0.y);
    o[2]=f2b(b2f(u[2])*r*w0.z); o[3]=f2b(b2f(u[3])*r*w0.w);
    o[4]=f2b(b2f(u[4])*r*w1.x); o[5]=f2b(b2f(u[5])*r*w1.y);
    o[6]=f2b(b2f(u[6])*r*w1.z); o[7]=f2b(b2f(u[7])*r*w1.w);
    *(uint4*)&XNb[(size_t)(m0+tk)*256 + idx] = *(const uint4*)o;
  }
}

// ---------------- LDS-staged bf16 MFMA GEMM (in-proj), BK=64: C = A @ W, bf16 out
template<int K>
__global__ __launch_bounds__(256) void gemm_mfma(
    const u16* __restrict__ Ab, const u16* __restrict__ WT,
    u16* __restrict__ Cv, int N)
{
  __shared__ u16 SH[2*128*72];          // 36864 B; epilogue reuses as [128][136]
  u16* As = SH;                         // [128][72]
  u16* Bs = SH + 128*72;
  const int tid = threadIdx.x;
  const int wave = tid >> 6, lane = tid & 63;
  const int quad = lane >> 4, l16 = lane & 15;
  const int bm0 = blockIdx.x*128, bn0 = blockIdx.y*128;
  const int wm = (wave & 1)*64, wn = (wave >> 1)*64;
  const int srow = tid >> 3, sch = (tid & 7)*8;
  floatx4 acc[4][4];
  #pragma unroll
  for (int r = 0; r < 4; ++r)
    #pragma unroll
    for (int c = 0; c < 4; ++c) acc[r][c] = (floatx4){0.f,0.f,0.f,0.f};

  for (int k0 = 0; k0 < K; k0 += 64) {
    #pragma unroll
    for (int p = 0; p < 4; ++p) {
      int row = srow + p*32;
      *(uint4*)&As[row*72 + sch] = *(const uint4*)&Ab[(size_t)(bm0+row)*K + k0 + sch];
      *(uint4*)&Bs[row*72 + sch] = *(const uint4*)&WT[(size_t)(bn0+row)*K + k0 + sch];
    }
    __syncthreads();
    #pragma unroll
    for (int ks = 0; ks < 2; ++ks) {
      bf16x8 af[4], bf[4];
      #pragma unroll
      for (int r = 0; r < 4; ++r)
        af[r] = *(const bf16x8*)&As[(wm + r*16 + l16)*72 + ks*32 + quad*8];
      #pragma unroll
      for (int c = 0; c < 4; ++c)
        bf[c] = *(const bf16x8*)&Bs[(wn + c*16 + l16)*72 + ks*32 + quad*8];
      #pragma unroll
      for (int r = 0; r < 4; ++r)
        #pragma unroll
        for (int c = 0; c < 4; ++c)
          acc[r][c] = __builtin_amdgcn_mfma_f32_16x16x32_bf16(af[r], bf[c], acc[r][c], 0, 0, 0);
    }
    __syncthreads();
  }
  u16* Cs = SH;                         // [128][136]
  #pragma unroll
  for (int c = 0; c < 4; ++c) {
    int nl = wn + c*16 + l16;
    #pragma unroll
    for (int r = 0; r < 4; ++r)
      #pragma unroll
      for (int reg = 0; reg < 4; ++reg) {
        int ml = wm + r*16 + quad*4 + reg;
        Cs[ml*136 + nl] = f2b(acc[r][c][reg]);
      }
  }
  __syncthreads();
  #pragma unroll
  for (int p = 0; p < 8; ++p) {
    int row = p*16 + (tid >> 4);
    int col = (tid & 15)*8;
    uint4 v = *(const uint4*)&Cs[row*136 + col];
    *(uint4*)&Cv[(size_t)(bm0+row)*N + bn0 + col] = v;
  }
}

// ---------------- x_dbl GEMM1 with fused causal conv+SiLU in the staging phase.
// Outputs BM, CM (fp32) and DTR fp32 [tok][16] (dt-rank, projected in the scans).
__global__ __launch_bounds__(256) void xdblBC_k(const u16* __restrict__ XZb,
    const float* __restrict__ cw, const float* __restrict__ cb,
    const u16* __restrict__ WxT,
    float* __restrict__ BM, float* __restrict__ CM, float* __restrict__ DTR)
{
  __shared__ u16 As[64*40];
  __shared__ u16 Ws[48*40];
  __shared__ float CWs[512*4];
  __shared__ float CBs[512];
  const int tid = threadIdx.x;
  const int wave = tid >> 6, lane = tid & 63;
  const int quad = lane >> 4, l16 = lane & 15;
  const int m0 = blockIdx.x*64;
  const int srow = tid >> 2, sch = (tid & 3)*8;
  const int n = m0 + srow;
  for (int e = tid; e < 2048; e += 256) CWs[e] = cw[e];
  for (int e = tid; e < 512;  e += 256) CBs[e] = cb[e];
  floatx4 acc[3];
  #pragma unroll
  for (int j = 0; j < 3; ++j) acc[j] = (floatx4){0.f,0.f,0.f,0.f};
  __syncthreads();
  const bf16x8 z8 = {0,0,0,0,0,0,0,0};
  for (int k0 = 0; k0 < DINNER; k0 += 32) {
    bf16x8 t3 = *(const bf16x8*)&XZb[(size_t)n*1024 + k0 + sch];
    bf16x8 t2 = z8, t1 = z8, t0v = z8;
    if (n >= 8)  t2  = *(const bf16x8*)&XZb[(size_t)(n-8)*1024  + k0 + sch];
    if (n >= 16) t1  = *(const bf16x8*)&XZb[(size_t)(n-16)*1024 + k0 + sch];
    if (n >= 24) t0v = *(const bf16x8*)&XZb[(size_t)(n-24)*1024 + k0 + sch];
    __align__(16) u16 outa[8];
    #pragma unroll
    for (int j = 0; j < 8; ++j) {
      int c = k0 + sch + j;
      float4 wv = *(const float4*)&CWs[c*4];
      float xc = CBs[c] + wv.x*b2f((u16)t0v[j]) + wv.y*b2f((u16)t1[j])
               + wv.z*b2f((u16)t2[j]) + wv.w*b2f((u16)t3[j]);
      outa[j] = f2b(siluf(xc));
    }
    *(uint4*)&As[srow*40 + sch] = *(const uint4*)outa;
    if (tid < 192) {
      int wr = tid >> 2;
      *(uint4*)&Ws[wr*40 + sch] = *(const uint4*)&WxT[(size_t)wr*512 + k0 + sch];
    }
    __syncthreads();
    bf16x8 af = *(const bf16x8*)&As[(wave*16 + l16)*40 + quad*8];
    #pragma unroll
    for (int j = 0; j < 3; ++j) {
      bf16x8 bf = *(const bf16x8*)&Ws[(j*16 + l16)*40 + quad*8];
      acc[j] = __builtin_amdgcn_mfma_f32_16x16x32_bf16(af, bf, acc[j], 0, 0, 0);
    }
    __syncthreads();
  }
  const int tok0 = m0 + wave*16;
  #pragma unroll
  for (int reg = 0; reg < 4; ++reg) {
    size_t t = (size_t)(tok0 + quad*4 + reg);
    BM[t*16 + l16]  = acc[1][reg];
    CM[t*16 + l16]  = acc[2][reg];
    DTR[t*16 + l16] = acc[0][reg];
  }
}

// ---------------- scan phase A: rolling conv + in-lane dt projection + h_end + sum(dt)
__global__ __launch_bounds__(256) void scanA_k(const float* __restrict__ DTR,
    const u16* __restrict__ XZb, const float* __restrict__ BM,
    const float* __restrict__ cw, const float* __restrict__ cb,
    const float* __restrict__ Wdt, const float* __restrict__ bdt,
    const float* __restrict__ Alog, u16* __restrict__ HENDb, float* __restrict__ DTS)
{
  __shared__ __align__(16) float Bs[SEGLEN*16];
  __shared__ __align__(16) float DRs[SEGLEN*16];
  const int tid = threadIdx.x;
  const int seg = blockIdx.x, b = blockIdx.y, half = blockIdx.z;
  const int c = half*256 + tid;
  const int t0 = seg*SEGLEN;
  {
    int t = tid >> 4, s = tid & 15;
    size_t nb = ((size_t)(t0+t)*BB + b)*16 + s;
    Bs[tid]  = BM[nb];
    DRs[tid] = DTR[nb];
  }
  float As[16];
  #pragma unroll
  for (int s = 0; s < 16; ++s) As[s] = -__expf(Alog[c*16+s]);
  bool uni = true;
  #pragma unroll
  for (int s = 1; s < 16; ++s)
    uni = uni && (fabsf(As[s] - As[0]*(float)(s+1)) <= 1e-4f*(float)(s+1));
  float wdt[16];
  #pragma unroll
  for (int r = 0; r < 16; ++r) wdt[r] = Wdt[r*DINNER + c];
  const float bd = bdt[c];
  const float4 cwv = *(const float4*)&cw[c*4];
  const float cbv = cb[c];
  float h[16];
  #pragma unroll
  for (int s = 0; s < 16; ++s) h[s] = 0.f;
  float dts = 0.f;
  __syncthreads();
  const size_t base = (size_t)t0*BB + b;
  const u16* xzp = XZb + base*1024 + c;
  float w0 = (t0 >= 3) ? b2f(xzp[-(size_t)3*BB*1024]) : 0.f;
  float w1 = (t0 >= 2) ? b2f(xzp[-(size_t)2*BB*1024]) : 0.f;
  float w2 = (t0 >= 1) ? b2f(xzp[-(size_t)1*BB*1024]) : 0.f;
  float xz = b2f(xzp[0]);
  for (int t = 0; t < SEGLEN; ++t) {
    float xzn = 0.f;
    if (t+1 < SEGLEN) xzn = b2f(xzp[(size_t)(t+1)*BB*1024]);
    // dt projection (DRs rows are wave-uniform broadcast)
    float dsum = bd;
    #pragma unroll
    for (int r = 0; r < 16; ++r) dsum = fmaf(DRs[t*16+r], wdt[r], dsum);
    float dt = (dsum > 20.f) ? dsum : __logf(1.f + __expf(dsum));
    float xp = siluf(cbv + cwv.x*w0 + cwv.y*w1 + cwv.z*w2 + cwv.w*xz);
    w0 = w1; w1 = w2; w2 = xz;
    dts += dt;
    float dtx = dt * xp;
    const float4 b0 = *(const float4*)&Bs[t*16+0];
    const float4 b1 = *(const float4*)&Bs[t*16+4];
    const float4 b2 = *(const float4*)&Bs[t*16+8];
    const float4 b3 = *(const float4*)&Bs[t*16+12];
    const float bv[16] = {b0.x,b0.y,b0.z,b0.w, b1.x,b1.y,b1.z,b1.w,
                          b2.x,b2.y,b2.z,b2.w, b3.x,b3.y,b3.z,b3.w};
    float dA[16];
    if (uni) {
      float p = __expf(dt*As[0]);
      dA[0] = p;
      #pragma unroll
      for (int s = 1; s < 16; ++s) dA[s] = dA[s-1]*p;
    } else {
      #pragma unroll
      for (int s = 0; s < 16; ++s) dA[s] = __expf(dt*As[s]);
    }
    #pragma unroll
    for (int s = 0; s < 16; ++s)
      h[s] = fmaf(dA[s], h[s], dtx*bv[s]);
    xz = xzn;
  }
  u16* hp = &HENDb[(((size_t)seg*BB + b)*DINNER + c)*16];
  #pragma unroll
  for (int q = 0; q < 2; ++q) {
    ushort4 v0, v1;
    v0.x = f2b(h[q*8+0]); v0.y = f2b(h[q*8+1]); v0.z = f2b(h[q*8+2]); v0.w = f2b(h[q*8+3]);
    v1.x = f2b(h[q*8+4]); v1.y = f2b(h[q*8+5]); v1.z = f2b(h[q*8+6]); v1.w = f2b(h[q*8+7]);
    *(ushort4*)&hp[q*8]     = v0;
    *(ushort4*)&hp[q*8 + 4] = v1;
  }
  DTS[((size_t)seg*BB + b)*DINNER + c] = dts;
}

// ---------------- stitch: sequential over NSEG segments, in-place HENDb -> h0
__global__ __launch_bounds__(256) void stitch_k(u16* __restrict__ HENDb,
    const float* __restrict__ DTS, const float* __restrict__ Alog)
{
  int g = blockIdx.x*256 + threadIdx.x;
  int b = g >> 13;
  int rem = g & 8191;          // c*16+s
  int cidx = rem >> 4;
  float A = -__expf(Alog[rem]);
  float h0 = 0.f;
  for (int k = 0; k < NSEG; ++k) {
    size_t idx = (((size_t)k*BB + b) << 13) + rem;
    float hend = b2f(HENDb[idx]);
    HENDb[idx] = f2b(h0);
    float dts = DTS[((size_t)k*BB + b)*DINNER + cidx];
    h0 = fmaf(__expf(dts*A), h0, hend);
  }
}

// ---------------- scan phase C: rolling conv + in-lane dt + full scan, gate, bf16 out
__global__ __launch_bounds__(256) void scanC_k(const float* __restrict__ DTR,
    const u16* __restrict__ XZb, const float* __restrict__ BM, const float* __restrict__ CM,
    const float* __restrict__ cw, const float* __restrict__ cb,
    const float* __restrict__ Wdt, const float* __restrict__ bdt,
    const float* __restrict__ Alog, const float* __restrict__ Dp,
    const u16* __restrict__ H0b, u16* __restrict__ YGb)
{
  __shared__ __align__(16) float Bs[SEGLEN*16];
  __shared__ __align__(16) float Cs[SEGLEN*16];
  __shared__ __align__(16) float DRs[SEGLEN*16];
  const int tid = threadIdx.x;
  const int seg = blockIdx.x, b = blockIdx.y, half = blockIdx.z;
  const int c = half*256 + tid;
  const int t0 = seg*SEGLEN;
  {
    int t = tid >> 4, s = tid & 15;
    size_t nb = ((size_t)(t0+t)*BB + b)*16 + s;
    Bs[tid]  = BM[nb];
    Cs[tid]  = CM[nb];
    DRs[tid] = DTR[nb];
  }
  float As[16];
  #pragma unroll
  for (int s = 0; s < 16; ++s) As[s] = -__expf(Alog[c*16+s]);
  bool uni = true;
  #pragma unroll
  for (int s = 1; s < 16; ++s)
    uni = uni && (fabsf(As[s] - As[0]*(float)(s+1)) <= 1e-4f*(float)(s+1));
  float wdt[16];
  #pragma unroll
  for (int r = 0; r < 16; ++r) wdt[r] = Wdt[r*DINNER + c];
  const float bd = bdt[c];
  const float4 cwv = *(const float4*)&cw[c*4];
  const float cbv = cb[c];
  float h[16];
  const u16* hp = &H0b[(((size_t)seg*BB + b)*DINNER + c)*16];
  #pragma unroll
  for (int q = 0; q < 4; ++q) {
    ushort4 hv = *(const ushort4*)&hp[q*4];
    h[q*4+0]=b2f(hv.x); h[q*4+1]=b2f(hv.y); h[q*4+2]=b2f(hv.z); h[q*4+3]=b2f(hv.w);
  }
  const float Dv = Dp[c];
  __syncthreads();
  const size_t base = (size_t)t0*BB + b;
  const u16* xzp = XZb + base*1024 + c;
  const u16* zp  = XZb + base*1024 + DINNER + c;
  u16*       ygp = YGb + base*DINNER + c;
  float w0 = (t0 >= 3) ? b2f(xzp[-(size_t)3*BB*1024]) : 0.f;
  float w1 = (t0 >= 2) ? b2f(xzp[-(size_t)2*BB*1024]) : 0.f;
  float w2 = (t0 >= 1) ? b2f(xzp[-(size_t)1*BB*1024]) : 0.f;
  float xz = b2f(xzp[0]);
  float zg = b2f(zp[0]);
  for (int t = 0; t < SEGLEN; ++t) {
    float xzn = 0.f, zgn = 0.f;
    if (t+1 < SEGLEN) {
      xzn = b2f(xzp[(size_t)(t+1)*BB*1024]);
      zgn = b2f(zp[(size_t)(t+1)*BB*1024]);
    }
    float dsum = bd;
    #pragma unroll
    for (int r = 0; r < 16; ++r) dsum = fmaf(DRs[t*16+r], wdt[r], dsum);
    float dt = (dsum > 20.f) ? dsum : __logf(1.f + __expf(dsum));
    float xp = siluf(cbv + cwv.x*w0 + cwv.y*w1 + cwv.z*w2 + cwv.w*xz);
    w0 = w1; w1 = w2; w2 = xz;
    float dtx = dt * xp;
    const float4 b0 = *(const float4*)&Bs[t*16+0];
    const float4 b1 = *(const float4*)&Bs[t*16+4];
    const float4 b2 = *(const float4*)&Bs[t*16+8];
    const float4 b3 = *(const float4*)&Bs[t*16+12];
    const float4 c0 = *(const float4*)&Cs[t*16+0];
    const float4 c1 = *(const float4*)&Cs[t*16+4];
    const float4 c2 = *(const float4*)&Cs[t*16+8];
    const float4 c3 = *(const float4*)&Cs[t*16+12];
    const float bvv[16] = {b0.x,b0.y,b0.z,b0.w, b1.x,b1.y,b1.z,b1.w,
                           b2.x,b2.y,b2.z,b2.w, b3.x,b3.y,b3.z,b3.w};
    const float cvv[16] = {c0.x,c0.y,c0.z,c0.w, c1.x,c1.y,c1.z,c1.w,
                           c2.x,c2.y,c2.z,c2.w, c3.x,c3.y,c3.z,c3.w};
    float dA[16];
    if (uni) {
      float p = __expf(dt*As[0]);
      dA[0] = p;
      #pragma unroll
      for (int s = 1; s < 16; ++s) dA[s] = dA[s-1]*p;
    } else {
      #pragma unroll
      for (int s = 0; s < 16; ++s) dA[s] = __expf(dt*As[s]);
    }
    float y0 = 0.f, y1 = 0.f, y2 = 0.f, y3 = 0.f;
    #pragma unroll
    for (int q = 0; q < 4; ++q) {
      h[q*4+0] = fmaf(dA[q*4+0], h[q*4+0], dtx*bvv[q*4+0]);
      h[q*4+1] = fmaf(dA[q*4+1], h[q*4+1], dtx*bvv[q*4+1]);
      h[q*4+2] = fmaf(dA[q*4+2], h[q*4+2], dtx*bvv[q*4+2]);
      h[q*4+3] = fmaf(dA[q*4+3], h[q*4+3], dtx*bvv[q*4+3]);
      y0 = fmaf(h[q*4+0], cvv[q*4+0], y0);
      y1 = fmaf(h[q*4+1], cvv[q*4+1], y1);
      y2 = fmaf(h[q*4+2], cvv[q*4+2], y2);
      y3 = fmaf(h[q*4+3], cvv[q*4+3], y3);
    }
    float y = (y0+y1) + (y2+y3);
    ygp[(size_t)t*BB*DINNER] = f2b((y + xp*Dv) * siluf(zg));
    xz = xzn; zg = zgn;
  }
}

// ---------------- fused out-proj (BK=64) + residual + action head + log-prob
__global__ __launch_bounds__(256) void outhead_k(const u16* __restrict__ YGb,
    const u16* __restrict__ WTo, const u16* __restrict__ Xb,
    const u16* __restrict__ WhT, const float* __restrict__ bh,
    const float* __restrict__ lstd, const float* __restrict__ a,
    float* __restrict__ out)
{
  __shared__ u16 SH[(64+256)*72];       // 46080 B staging; epilogue [64][264]=16896 u16
  u16* As = SH;                         // [64][72]
  u16* Bs = SH + 64*72;                 // [256][72]
  const int tid = threadIdx.x;
  const int wave = tid >> 6, lane = tid & 63;
  const int quad = lane >> 4, l16 = lane & 15;
  const int m0 = blockIdx.x*64;
  const int n0 = wave*64;
  const int srow = tid >> 3, sch = (tid & 7)*8;
  floatx4 acc[4][4];
  #pragma unroll
  for (int r = 0; r < 4; ++r)
    #pragma unroll
    for (int c = 0; c < 4; ++c) acc[r][c] = (floatx4){0.f,0.f,0.f,0.f};

  for (int k0 = 0; k0 < DINNER; k0 += 64) {
    #pragma unroll
    for (int p = 0; p < 2; ++p) {
      int row = srow + p*32;
      *(uint4*)&As[row*72 + sch] = *(const uint4*)&YGb[(size_t)(m0+row)*DINNER + k0 + sch];
    }
    #pragma unroll
    for (int p = 0; p < 8; ++p) {
      int row = srow + p*32;
      *(uint4*)&Bs[row*72 + sch] = *(const uint4*)&WTo[(size_t)row*DINNER + k0 + sch];
    }
    __syncthreads();
    #pragma unroll
    for (int ks = 0; ks < 2; ++ks) {
      bf16x8 af[4], bf[4];
      #pragma unroll
      for (int r = 0; r < 4; ++r)
        af[r] = *(const bf16x8*)&As[(r*16 + l16)*72 + ks*32 + quad*8];
      #pragma unroll
      for (int c = 0; c < 4; ++c)
        bf[c] = *(const bf16x8*)&Bs[(n0 + c*16 + l16)*72 + ks*32 + quad*8];
      #pragma unroll
      for (int r = 0; r < 4; ++r)
        #pragma unroll
        for (int c = 0; c < 4; ++c)
          acc[r][c] = __builtin_amdgcn_mfma_f32_16x16x32_bf16(af[r], bf[c], acc[r][c], 0, 0, 0);
    }
    __syncthreads();
  }
  u16* Xs = SH;                         // [64][264]
  #pragma unroll
  for (int p = 0; p < 8; ++p) {
    int row = p*8 + (tid >> 5);
    int col = (tid & 31)*8;
    *(uint4*)&Xs[row*264 + col] = *(const uint4*)&Xb[(size_t)(m0+row)*256 + col];
  }
  __syncthreads();
  #pragma unroll
  for (int c = 0; c < 4; ++c) {
    int n = n0 + c*16 + l16;
    #pragma unroll
    for (int r = 0; r < 4; ++r) {
      #pragma unroll
      for (int reg = 0; reg < 4; ++reg) {
        int ml = r*16 + quad*4 + reg;
        Xs[ml*264 + n] = f2b(acc[r][c][reg] + b2f(Xs[ml*264 + n]));
      }
    }
  }
  __syncthreads();
  floatx4 mu[2];
  mu[0] = (floatx4){0.f,0.f,0.f,0.f};
  mu[1] = (floatx4){0.f,0.f,0.f,0.f};
  #pragma unroll
  for (int k0 = 0; k0 < DMODEL; k0 += 32) {
    bf16x8 axf = *(const bf16x8*)&Xs[(wave*16 + l16)*264 + k0 + quad*8];
    #pragma unroll
    for (int nt = 0; nt < 2; ++nt) {
      bf16x8 bwf = *(const bf16x8*)(WhT + (size_t)(nt*16 + l16)*DMODEL + k0 + quad*8);
      mu[nt] = __builtin_amdgcn_mfma_f32_16x16x32_bf16(axf, bwf, mu[nt], 0, 0, 0);
    }
  }
  float ls0 = lstd[l16],      els0 = __expf(-ls0), bh0 = bh[l16];
  float ls1 = lstd[16 + l16], els1 = __expf(-ls1), bh1 = bh[16 + l16];
  #pragma unroll
  for (int reg = 0; reg < 4; ++reg) {
    int tok = m0 + wave*16 + quad*4 + reg;
    float m0v = mu[0][reg] + bh0;
    float m1v = mu[1][reg] + bh1;
    float z0 = (a[(size_t)tok*32 + l16]      - m0v) * els0;
    float z1 = (a[(size_t)tok*32 + 16 + l16] - m1v) * els1;
    float t = (-0.5f*z0*z0 - ls0) + (-0.5f*z1*z1 - ls1) - 2.f*0.91893853320467274f;
    t += __shfl_xor(t, 1);
    t += __shfl_xor(t, 2);
    t += __shfl_xor(t, 4);
    t += __shfl_xor(t, 8);
    if (l16 == 0) out[tok] = t;
  }
}

extern "C" void kernel_launch(void* const* d_in, const int* in_sizes, int n_in,
                              void* d_out, int out_size, void* d_ws, size_t ws_size,
                              hipStream_t stream)
{
  const float* s    = (const float*)d_in[0];
  const float* a    = (const float*)d_in[1];
  const float* Wemb = (const float*)d_in[2];
  const float* bemb = (const float*)d_in[3];
  const float* nw   = (const float*)d_in[4];
  const float* Win  = (const float*)d_in[5];
  const float* cw   = (const float*)d_in[6];
  const float* cb   = (const float*)d_in[7];
  const float* Wx   = (const float*)d_in[8];
  const float* Wdt  = (const float*)d_in[9];
  const float* bdt  = (const float*)d_in[10];
  const float* Alog = (const float*)d_in[11];
  const float* Dp   = (const float*)d_in[12];
  const float* Wout = (const float*)d_in[13];
  const float* Wh   = (const float*)d_in[14];
  const float* bh   = (const float*)d_in[15];
  const float* lstd = (const float*)d_in[16];

  // -------- workspace layout (~105 MB)
  u16*   Xb   = (u16*)d_ws;                         // NTOK*256 bf16 (emb resid)
  u16*   XZb  = Xb  + (size_t)NTOK*DMODEL;          // NTOK*1024 bf16 [xp|z]
  u16*   XNb  = XZb + (size_t)NTOK*1024;            // NTOK*256 bf16
  u16*   YGb  = XNb + (size_t)NTOK*DMODEL;          // NTOK*512 bf16
  u16*   WTe  = YGb + (size_t)NTOK*DINNER;          // 256*128
  u16*   WTi  = WTe + 256*128;                      // 1024*256
  u16*   WTo  = WTi + 1024*256;                     // 256*512
  u16*   WxT  = WTo + 256*512;                      // 48*512
  u16*   WhT  = WxT + 48*512;                       // 32*256
  u16*   HENDb= WhT + 32*256;                       // NSEG*8*512*16 bf16
  float* BM   = (float*)(HENDb + (size_t)NSEG*BB*DINNER*16); // NTOK*16 fp32
  float* CM   = BM + (size_t)NTOK*16;               // NTOK*16 fp32
  float* DTR  = CM + (size_t)NTOK*16;               // NTOK*16 fp32
  float* DTS  = DTR + (size_t)NTOK*16;              // NSEG*8*512 fp32
  float* out  = (float*)d_out;

  prep_k        <<<1792,        256, 0, stream>>>(Wemb, Win, Wout, Wx, Wh,
                                                  WTe, WTi, WTo, WxT, WhT);
  embnorm_k     <<<256,         256, 0, stream>>>(s, WTe, bemb, nw, Xb, XNb);
  gemm_mfma<256><<<dim3(128,8), 256, 0, stream>>>(XNb, WTi, XZb, 1024);
  xdblBC_k      <<<256,         256, 0, stream>>>(XZb, cw, cb, WxT, BM, CM, DTR);
  scanA_k       <<<dim3(NSEG,BB,2), 256, 0, stream>>>(DTR, XZb, BM, cw, cb, Wdt, bdt,
                                                      Alog, HENDb, DTS);
  stitch_k      <<<256,         256, 0, stream>>>(HENDb, DTS, Alog);
  scanC_k       <<<dim3(NSEG,BB,2), 256, 0, stream>>>(DTR, XZb, BM, CM, cw, cb, Wdt, bdt,
                                                      Alog, Dp, HENDb, YGb);
  outhead_k     <<<256,         256, 0, stream>>>(YGb, WTo, Xb, WhT, bh, lstd, a, out);
}

// Round 15
// 248.434 us; speedup vs baseline: 1.0120x; 1.0120x over previous
//
#include <hip/hip_runtime.h>

typedef unsigned short u16;
typedef short bf16x8 __attribute__((ext_vector_type(8)));   // 8 bf16 = 4 VGPR
typedef float floatx4 __attribute__((ext_vector_type(4)));

#define LSEQ 2048
#define BB 8
#define NTOK (LSEQ*BB)        // 16384 tokens, n = l*B + b
#define DMODEL 256
#define DINNER 512
#define NSEG 128
#define SEGLEN 16             // LSEQ / NSEG

__device__ __forceinline__ float siluf(float x){ return x / (1.f + __expf(-x)); }
__device__ __forceinline__ float b2f(u16 x){ return __uint_as_float(((unsigned)x) << 16); }
__device__ __forceinline__ u16 f2b(float f){
  unsigned u = __float_as_uint(f);
  unsigned r = (u + 0x7fffu + ((u >> 16) & 1u)) >> 16;
  return (u16)r;
}

// ---------------- prep: 5 weight transpose/casts, range-switched
__global__ __launch_bounds__(256) void prep_k(
    const float* __restrict__ Wemb, const float* __restrict__ Win,
    const float* __restrict__ Wout, const float* __restrict__ Wx,
    const float* __restrict__ Wh,
    u16* __restrict__ WTe, u16* __restrict__ WTi, u16* __restrict__ WTo,
    u16* __restrict__ WxT, u16* __restrict__ WhT)
{
  int g = blockIdx.x, tid = threadIdx.x;
  if (g < 128) {                        // WTe[n][k], n<256, k<128
    int idx = g*256 + tid; int n = idx >> 7, k = idx & 127;
    WTe[idx] = f2b(Wemb[(size_t)k*256 + n]);
  } else if (g < 1152) {                // WTi[n][k], n<1024, k<256
    int idx = (g-128)*256 + tid; int n = idx >> 8, k = idx & 255;
    WTi[idx] = f2b(Win[(size_t)k*1024 + n]);
  } else if (g < 1664) {                // WTo[n][k], n<256, k<512
    int idx = (g-1152)*256 + tid; int n = idx >> 9, k = idx & 511;
    WTo[idx] = f2b(Wout[(size_t)k*256 + n]);
  } else if (g < 1760) {                // WxT[48][512]
    int idx = (g-1664)*256 + tid; int n = idx >> 9, k = idx & 511;
    WxT[idx] = f2b(Wx[(size_t)k*48 + n]);
  } else {                              // WhT[32][256]
    int idx = (g-1760)*256 + tid; int j = idx >> 8, k = idx & 255;
    WhT[idx] = f2b(Wh[(size_t)k*32 + j]);
  }
}

// ---------------- fused emb GEMM + RMSNorm: block = 64 tokens x full N=256.
__global__ __launch_bounds__(256) void embnorm_k(
    const float* __restrict__ s, const u16* __restrict__ WTe,
    const float* __restrict__ bemb, const float* __restrict__ nw,
    u16* __restrict__ Xb, u16* __restrict__ XNb)
{
  __shared__ u16 SH[64*264];
  __shared__ float ssq[64*4];
  __shared__ float rr[64];
  u16* As = SH;
  u16* Bs = SH + 64*40;
  const int tid = threadIdx.x;
  const int wave = tid >> 6, lane = tid & 63;
  const int quad = lane >> 4, l16 = lane & 15;
  const int m0 = blockIdx.x*64;
  const int wn = wave*64;
  const int srow = tid >> 2, sch = (tid & 3)*8;
  floatx4 acc[4][4];
  #pragma unroll
  for (int r = 0; r < 4; ++r)
    #pragma unroll
    for (int c = 0; c < 4; ++c) acc[r][c] = (floatx4){0.f,0.f,0.f,0.f};

  for (int k0 = 0; k0 < 128; k0 += 32) {
    {
      float4 v0 = *(const float4*)&s[(size_t)(m0+srow)*128 + k0 + sch];
      float4 v1 = *(const float4*)&s[(size_t)(m0+srow)*128 + k0 + sch + 4];
      __align__(16) u16 o[8];
      o[0]=f2b(v0.x); o[1]=f2b(v0.y); o[2]=f2b(v0.z); o[3]=f2b(v0.w);
      o[4]=f2b(v1.x); o[5]=f2b(v1.y); o[6]=f2b(v1.z); o[7]=f2b(v1.w);
      *(uint4*)&As[srow*40 + sch] = *(const uint4*)o;
    }
    #pragma unroll
    for (int p = 0; p < 4; ++p) {
      int row = srow + p*64;
      *(uint4*)&Bs[row*40 + sch] = *(const uint4*)&WTe[(size_t)row*128 + k0 + sch];
    }
    __syncthreads();
    bf16x8 af[4], bf[4];
    #pragma unroll
    for (int r = 0; r < 4; ++r) af[r] = *(const bf16x8*)&As[(r*16 + l16)*40 + quad*8];
    #pragma unroll
    for (int c = 0; c < 4; ++c) bf[c] = *(const bf16x8*)&Bs[(wn + c*16 + l16)*40 + quad*8];
    #pragma unroll
    for (int r = 0; r < 4; ++r)
      #pragma unroll
      for (int c = 0; c < 4; ++c)
        acc[r][c] = __builtin_amdgcn_mfma_f32_16x16x32_bf16(af[r], bf[c], acc[r][c], 0, 0, 0);
    __syncthreads();
  }
  u16* Xs = SH;                         // [64][264]
  #pragma unroll
  for (int c = 0; c < 4; ++c) {
    int n = wn + c*16 + l16;
    float bv = bemb[n];
    #pragma unroll
    for (int r = 0; r < 4; ++r)
      #pragma unroll
      for (int reg = 0; reg < 4; ++reg) {
        int ml = r*16 + quad*4 + reg;
        Xs[ml*264 + n] = f2b(acc[r][c][reg] + bv);
      }
  }
  __syncthreads();
  #pragma unroll
  for (int p = 0; p < 8; ++p) {
    int row = p*8 + (tid >> 5);
    int col = (tid & 31)*8;
    *(uint4*)&Xb[(size_t)(m0+row)*256 + col] = *(const uint4*)&Xs[row*264 + col];
  }
  const int tk = tid >> 2, q = tid & 3;
  float ss = 0.f;
  #pragma unroll
  for (int j = 0; j < 8; ++j) {
    uint4 v = *(const uint4*)&Xs[tk*264 + q*64 + j*8];
    const u16* u = (const u16*)&v;
    #pragma unroll
    for (int i = 0; i < 8; ++i) { float x = b2f(u[i]); ss += x*x; }
  }
  ssq[tk*4 + q] = ss;
  __syncthreads();
  if (q == 0)
    rr[tk] = rsqrtf((ssq[tk*4]+ssq[tk*4+1]+ssq[tk*4+2]+ssq[tk*4+3])*(1.f/DMODEL) + 1e-5f);
  __syncthreads();
  float r = rr[tk];
  #pragma unroll
  for (int j = 0; j < 8; ++j) {
    int idx = q*64 + j*8;
    uint4 v = *(const uint4*)&Xs[tk*264 + idx];
    const u16* u = (const u16*)&v;
    float4 w0 = *(const float4*)&nw[idx];
    float4 w1 = *(const float4*)&nw[idx+4];
    __align__(16) u16 o[8];
    o[0]=f2b(b2f(u[0])*r*w0.x); o[1]=f2b(b2f(u[1])*r*w0.y);
    o[2]=f2b(b2f(u[2])*r*w0.z); o[3]=f2b(b2f(u[3])*r*w0.w);
    o[4]=f2b(b2f(u[4])*r*w1.x); o[5]=f2b(b2f(u[5])*r*w1.y);
    o[6]=f2b(b2f(u[6])*r*w1.z); o[7]=f2b(b2f(u[7])*r*w1.w);
    *(uint4*)&XNb[(size_t)(m0+tk)*256 + idx] = *(const uint4*)o;
  }
}

// ---------------- LDS-staged bf16 MFMA GEMM (in-proj), BK=64: C = A @ W, bf16 out
template<int K>
__global__ __launch_bounds__(256) void gemm_mfma(
    const u16* __restrict__ Ab, const u16* __restrict__ WT,
    u16* __restrict__ Cv, int N)
{
  __shared__ u16 SH[2*128*72];
  u16* As = SH;
  u16* Bs = SH + 128*72;
  const int tid = threadIdx.x;
  const int wave = tid >> 6, lane = tid & 63;
  const int quad = lane >> 4, l16 = lane & 15;
  const int bm0 = blockIdx.x*128, bn0 = blockIdx.y*128;
  const int wm = (wave & 1)*64, wn = (wave >> 1)*64;
  const int srow = tid >> 3, sch = (tid & 7)*8;
  floatx4 acc[4][4];
  #pragma unroll
  for (int r = 0; r < 4; ++r)
    #pragma unroll
    for (int c = 0; c < 4; ++c) acc[r][c] = (floatx4){0.f,0.f,0.f,0.f};

  for (int k0 = 0; k0 < K; k0 += 64) {
    #pragma unroll
    for (int p = 0; p < 4; ++p) {
      int row = srow + p*32;
      *(uint4*)&As[row*72 + sch] = *(const uint4*)&Ab[(size_t)(bm0+row)*K + k0 + sch];
      *(uint4*)&Bs[row*72 + sch] = *(const uint4*)&WT[(size_t)(bn0+row)*K + k0 + sch];
    }
    __syncthreads();
    #pragma unroll
    for (int ks = 0; ks < 2; ++ks) {
      bf16x8 af[4], bf[4];
      #pragma unroll
      for (int r = 0; r < 4; ++r)
        af[r] = *(const bf16x8*)&As[(wm + r*16 + l16)*72 + ks*32 + quad*8];
      #pragma unroll
      for (int c = 0; c < 4; ++c)
        bf[c] = *(const bf16x8*)&Bs[(wn + c*16 + l16)*72 + ks*32 + quad*8];
      #pragma unroll
      for (int r = 0; r < 4; ++r)
        #pragma unroll
        for (int c = 0; c < 4; ++c)
          acc[r][c] = __builtin_amdgcn_mfma_f32_16x16x32_bf16(af[r], bf[c], acc[r][c], 0, 0, 0);
    }
    __syncthreads();
  }
  u16* Cs = SH;                         // [128][136]
  #pragma unroll
  for (int c = 0; c < 4; ++c) {
    int nl = wn + c*16 + l16;
    #pragma unroll
    for (int r = 0; r < 4; ++r)
      #pragma unroll
      for (int reg = 0; reg < 4; ++reg) {
        int ml = wm + r*16 + quad*4 + reg;
        Cs[ml*136 + nl] = f2b(acc[r][c][reg]);
      }
  }
  __syncthreads();
  #pragma unroll
  for (int p = 0; p < 8; ++p) {
    int row = p*16 + (tid >> 4);
    int col = (tid & 15)*8;
    uint4 v = *(const uint4*)&Cs[row*136 + col];
    *(uint4*)&Cv[(size_t)(bm0+row)*N + bn0 + col] = v;
  }
}

// ---------------- x_dbl GEMM1 with fused causal conv+SiLU in the staging phase.
__global__ __launch_bounds__(256) void xdblBC_k(const u16* __restrict__ XZb,
    const float* __restrict__ cw, const float* __restrict__ cb,
    const u16* __restrict__ WxT,
    float* __restrict__ BM, float* __restrict__ CM, float* __restrict__ DTR)
{
  __shared__ u16 As[64*40];
  __shared__ u16 Ws[48*40];
  __shared__ float CWs[512*4];
  __shared__ float CBs[512];
  const int tid = threadIdx.x;
  const int wave = tid >> 6, lane = tid & 63;
  const int quad = lane >> 4, l16 = lane & 15;
  const int m0 = blockIdx.x*64;
  const int srow = tid >> 2, sch = (tid & 3)*8;
  const int n = m0 + srow;
  for (int e = tid; e < 2048; e += 256) CWs[e] = cw[e];
  for (int e = tid; e < 512;  e += 256) CBs[e] = cb[e];
  floatx4 acc[3];
  #pragma unroll
  for (int j = 0; j < 3; ++j) acc[j] = (floatx4){0.f,0.f,0.f,0.f};
  __syncthreads();
  const bf16x8 z8 = {0,0,0,0,0,0,0,0};
  for (int k0 = 0; k0 < DINNER; k0 += 32) {
    bf16x8 t3 = *(const bf16x8*)&XZb[(size_t)n*1024 + k0 + sch];
    bf16x8 t2 = z8, t1 = z8, t0v = z8;
    if (n >= 8)  t2  = *(const bf16x8*)&XZb[(size_t)(n-8)*1024  + k0 + sch];
    if (n >= 16) t1  = *(const bf16x8*)&XZb[(size_t)(n-16)*1024 + k0 + sch];
    if (n >= 24) t0v = *(const bf16x8*)&XZb[(size_t)(n-24)*1024 + k0 + sch];
    __align__(16) u16 outa[8];
    #pragma unroll
    for (int j = 0; j < 8; ++j) {
      int c = k0 + sch + j;
      float4 wv = *(const float4*)&CWs[c*4];
      float xc = CBs[c] + wv.x*b2f((u16)t0v[j]) + wv.y*b2f((u16)t1[j])
               + wv.z*b2f((u16)t2[j]) + wv.w*b2f((u16)t3[j]);
      outa[j] = f2b(siluf(xc));
    }
    *(uint4*)&As[srow*40 + sch] = *(const uint4*)outa;
    if (tid < 192) {
      int wr = tid >> 2;
      *(uint4*)&Ws[wr*40 + sch] = *(const uint4*)&WxT[(size_t)wr*512 + k0 + sch];
    }
    __syncthreads();
    bf16x8 af = *(const bf16x8*)&As[(wave*16 + l16)*40 + quad*8];
    #pragma unroll
    for (int j = 0; j < 3; ++j) {
      bf16x8 bf = *(const bf16x8*)&Ws[(j*16 + l16)*40 + quad*8];
      acc[j] = __builtin_amdgcn_mfma_f32_16x16x32_bf16(af, bf, acc[j], 0, 0, 0);
    }
    __syncthreads();
  }
  const int tok0 = m0 + wave*16;
  #pragma unroll
  for (int reg = 0; reg < 4; ++reg) {
    size_t t = (size_t)(tok0 + quad*4 + reg);
    BM[t*16 + l16]  = acc[1][reg];
    CM[t*16 + l16]  = acc[2][reg];
    DTR[t*16 + l16] = acc[0][reg];
  }
}

// ---------------- scan phase A: rolling conv + dt projection (uniform s_loads),
// stores h_end (bf16), sum(dt), and packed {dt,xp} bf16x2 for scanC.
__global__ __launch_bounds__(256) void scanA_k(const float* __restrict__ DTR,
    const u16* __restrict__ XZb, const float* __restrict__ BM,
    const float* __restrict__ cw, const float* __restrict__ cb,
    const float* __restrict__ Wdt, const float* __restrict__ bdt,
    const float* __restrict__ Alog, u16* __restrict__ HENDb, float* __restrict__ DTS,
    unsigned* __restrict__ DXb)
{
  const int tid = threadIdx.x;
  const int seg = blockIdx.x, b = blockIdx.y, half = blockIdx.z;
  const int c = half*256 + tid;
  const int t0 = seg*SEGLEN;
  float As[16];
  #pragma unroll
  for (int s = 0; s < 16; ++s) As[s] = -__expf(Alog[c*16+s]);
  bool uni = true;
  #pragma unroll
  for (int s = 1; s < 16; ++s)
    uni = uni && (fabsf(As[s] - As[0]*(float)(s+1)) <= 1e-4f*(float)(s+1));
  float wdt[16];
  #pragma unroll
  for (int r = 0; r < 16; ++r) wdt[r] = Wdt[r*DINNER + c];
  const float bd = bdt[c];
  const float4 cwv = *(const float4*)&cw[c*4];
  const float cbv = cb[c];
  float h[16];
  #pragma unroll
  for (int s = 0; s < 16; ++s) h[s] = 0.f;
  float dts = 0.f;
  const size_t base = (size_t)t0*BB + b;
  const u16* xzp = XZb + base*1024 + c;
  float w0 = (t0 >= 3) ? b2f(xzp[-(size_t)3*BB*1024]) : 0.f;
  float w1 = (t0 >= 2) ? b2f(xzp[-(size_t)2*BB*1024]) : 0.f;
  float w2 = (t0 >= 1) ? b2f(xzp[-(size_t)1*BB*1024]) : 0.f;
  float xz = b2f(xzp[0]);
  for (int t = 0; t < SEGLEN; ++t) {
    float xzn = 0.f;
    if (t+1 < SEGLEN) xzn = b2f(xzp[(size_t)(t+1)*BB*1024]);
    size_t nb16 = ((size_t)(t0+t)*BB + b)*16;
    // uniform s_loads: B row + dtr row
    const float4 b0 = *(const float4*)&BM[nb16+0];
    const float4 b1 = *(const float4*)&BM[nb16+4];
    const float4 b2 = *(const float4*)&BM[nb16+8];
    const float4 b3 = *(const float4*)&BM[nb16+12];
    const float4 d0 = *(const float4*)&DTR[nb16+0];
    const float4 d1 = *(const float4*)&DTR[nb16+4];
    const float4 d2 = *(const float4*)&DTR[nb16+8];
    const float4 d3 = *(const float4*)&DTR[nb16+12];
    float dsum = bd;
    dsum = fmaf(d0.x,wdt[0],dsum);  dsum = fmaf(d0.y,wdt[1],dsum);
    dsum = fmaf(d0.z,wdt[2],dsum);  dsum = fmaf(d0.w,wdt[3],dsum);
    dsum = fmaf(d1.x,wdt[4],dsum);  dsum = fmaf(d1.y,wdt[5],dsum);
    dsum = fmaf(d1.z,wdt[6],dsum);  dsum = fmaf(d1.w,wdt[7],dsum);
    dsum = fmaf(d2.x,wdt[8],dsum);  dsum = fmaf(d2.y,wdt[9],dsum);
    dsum = fmaf(d2.z,wdt[10],dsum); dsum = fmaf(d2.w,wdt[11],dsum);
    dsum = fmaf(d3.x,wdt[12],dsum); dsum = fmaf(d3.y,wdt[13],dsum);
    dsum = fmaf(d3.z,wdt[14],dsum); dsum = fmaf(d3.w,wdt[15],dsum);
    float dt = (dsum > 20.f) ? dsum : __logf(1.f + __expf(dsum));
    float xp = siluf(cbv + cwv.x*w0 + cwv.y*w1 + cwv.z*w2 + cwv.w*xz);
    w0 = w1; w1 = w2; w2 = xz;
    dts += dt;
    DXb[(((size_t)(t0+t)*BB + b)*DINNER + c)] = ((unsigned)f2b(xp) << 16) | f2b(dt);
    float dtx = dt * xp;
    const float bv[16] = {b0.x,b0.y,b0.z,b0.w, b1.x,b1.y,b1.z,b1.w,
                          b2.x,b2.y,b2.z,b2.w, b3.x,b3.y,b3.z,b3.w};
    float dA[16];
    if (uni) {
      float p = __expf(dt*As[0]);
      float p2 = p*p, p4 = p2*p2, p8 = p4*p4;
      dA[0]=p;      dA[1]=p2;     dA[2]=p2*p;   dA[3]=p4;
      dA[4]=p4*p;   dA[5]=p4*p2;  dA[6]=p4*p2*p;dA[7]=p8;
      dA[8]=p8*p;   dA[9]=p8*p2;  dA[10]=p8*p2*p; dA[11]=p8*p4;
      dA[12]=p8*p4*p; dA[13]=p8*p4*p2; dA[14]=p8*p4*p2*p; dA[15]=p8*p8;
    } else {
      #pragma unroll
      for (int s = 0; s < 16; ++s) dA[s] = __expf(dt*As[s]);
    }
    #pragma unroll
    for (int s = 0; s < 16; ++s)
      h[s] = fmaf(dA[s], h[s], dtx*bv[s]);
    xz = xzn;
  }
  u16* hp = &HENDb[(((size_t)seg*BB + b)*DINNER + c)*16];
  #pragma unroll
  for (int q = 0; q < 2; ++q) {
    ushort4 v0, v1;
    v0.x = f2b(h[q*8+0]); v0.y = f2b(h[q*8+1]); v0.z = f2b(h[q*8+2]); v0.w = f2b(h[q*8+3]);
    v1.x = f2b(h[q*8+4]); v1.y = f2b(h[q*8+5]); v1.z = f2b(h[q*8+6]); v1.w = f2b(h[q*8+7]);
    *(ushort4*)&hp[q*8]     = v0;
    *(ushort4*)&hp[q*8 + 4] = v1;
  }
  DTS[((size_t)seg*BB + b)*DINNER + c] = dts;
}

// ---------------- stitch: sequential over NSEG segments, in-place HENDb -> h0
__global__ __launch_bounds__(256) void stitch_k(u16* __restrict__ HENDb,
    const float* __restrict__ DTS, const float* __restrict__ Alog)
{
  int g = blockIdx.x*256 + threadIdx.x;
  int b = g >> 13;
  int rem = g & 8191;          // c*16+s
  int cidx = rem >> 4;
  float A = -__expf(Alog[rem]);
  float h0 = 0.f;
  for (int k = 0; k < NSEG; ++k) {
    size_t idx = (((size_t)k*BB + b) << 13) + rem;
    float hend = b2f(HENDb[idx]);
    HENDb[idx] = f2b(h0);
    float dts = DTS[((size_t)k*BB + b)*DINNER + cidx];
    h0 = fmaf(__expf(dts*A), h0, hend);
  }
}

// ---------------- scan phase C: loads packed {dt,xp}; uniform s_loads for B/C;
// full scan with h0, gate, bf16 out. No LDS, no conv/dt recompute.
__global__ __launch_bounds__(256) void scanC_k(const unsigned* __restrict__ DXb,
    const u16* __restrict__ XZb, const float* __restrict__ BM, const float* __restrict__ CM,
    const float* __restrict__ Alog, const float* __restrict__ Dp,
    const u16* __restrict__ H0b, u16* __restrict__ YGb)
{
  const int tid = threadIdx.x;
  const int seg = blockIdx.x, b = blockIdx.y, half = blockIdx.z;
  const int c = half*256 + tid;
  const int t0 = seg*SEGLEN;
  float As[16];
  #pragma unroll
  for (int s = 0; s < 16; ++s) As[s] = -__expf(Alog[c*16+s]);
  bool uni = true;
  #pragma unroll
  for (int s = 1; s < 16; ++s)
    uni = uni && (fabsf(As[s] - As[0]*(float)(s+1)) <= 1e-4f*(float)(s+1));
  float h[16];
  const u16* hp = &H0b[(((size_t)seg*BB + b)*DINNER + c)*16];
  #pragma unroll
  for (int q = 0; q < 4; ++q) {
    ushort4 hv = *(const ushort4*)&hp[q*4];
    h[q*4+0]=b2f(hv.x); h[q*4+1]=b2f(hv.y); h[q*4+2]=b2f(hv.z); h[q*4+3]=b2f(hv.w);
  }
  const float Dv = Dp[c];
  const size_t base = (size_t)t0*BB + b;
  const unsigned* dxp = DXb + base*DINNER + c;
  const u16* zp  = XZb + base*1024 + DINNER + c;
  u16*       ygp = YGb + base*DINNER + c;
  unsigned dx = dxp[0];
  float zg = b2f(zp[0]);
  for (int t = 0; t < SEGLEN; ++t) {
    unsigned dxn = 0; float zgn = 0.f;
    if (t+1 < SEGLEN) {
      dxn = dxp[(size_t)(t+1)*BB*DINNER];
      zgn = b2f(zp[(size_t)(t+1)*BB*1024]);
    }
    float dt = __uint_as_float(dx << 16);
    float xp = __uint_as_float(dx & 0xffff0000u);
    size_t nb16 = ((size_t)(t0+t)*BB + b)*16;
    const float4 b0 = *(const float4*)&BM[nb16+0];
    const float4 b1 = *(const float4*)&BM[nb16+4];
    const float4 b2 = *(const float4*)&BM[nb16+8];
    const float4 b3 = *(const float4*)&BM[nb16+12];
    const float4 c0 = *(const float4*)&CM[nb16+0];
    const float4 c1 = *(const float4*)&CM[nb16+4];
    const float4 c2 = *(const float4*)&CM[nb16+8];
    const float4 c3 = *(const float4*)&CM[nb16+12];
    const float bvv[16] = {b0.x,b0.y,b0.z,b0.w, b1.x,b1.y,b1.z,b1.w,
                           b2.x,b2.y,b2.z,b2.w, b3.x,b3.y,b3.z,b3.w};
    const float cvv[16] = {c0.x,c0.y,c0.z,c0.w, c1.x,c1.y,c1.z,c1.w,
                           c2.x,c2.y,c2.z,c2.w, c3.x,c3.y,c3.z,c3.w};
    float dtx = dt * xp;
    float dA[16];
    if (uni) {
      float p = __expf(dt*As[0]);
      float p2 = p*p, p4 = p2*p2, p8 = p4*p4;
      dA[0]=p;      dA[1]=p2;     dA[2]=p2*p;   dA[3]=p4;
      dA[4]=p4*p;   dA[5]=p4*p2;  dA[6]=p4*p2*p;dA[7]=p8;
      dA[8]=p8*p;   dA[9]=p8*p2;  dA[10]=p8*p2*p; dA[11]=p8*p4;
      dA[12]=p8*p4*p; dA[13]=p8*p4*p2; dA[14]=p8*p4*p2*p; dA[15]=p8*p8;
    } else {
      #pragma unroll
      for (int s = 0; s < 16; ++s) dA[s] = __expf(dt*As[s]);
    }
    float y0 = 0.f, y1 = 0.f, y2 = 0.f, y3 = 0.f;
    #pragma unroll
    for (int q = 0; q < 4; ++q) {
      h[q*4+0] = fmaf(dA[q*4+0], h[q*4+0], dtx*bvv[q*4+0]);
      h[q*4+1] = fmaf(dA[q*4+1], h[q*4+1], dtx*bvv[q*4+1]);
      h[q*4+2] = fmaf(dA[q*4+2], h[q*4+2], dtx*bvv[q*4+2]);
      h[q*4+3] = fmaf(dA[q*4+3], h[q*4+3], dtx*bvv[q*4+3]);
      y0 = fmaf(h[q*4+0], cvv[q*4+0], y0);
      y1 = fmaf(h[q*4+1], cvv[q*4+1], y1);
      y2 = fmaf(h[q*4+2], cvv[q*4+2], y2);
      y3 = fmaf(h[q*4+3], cvv[q*4+3], y3);
    }
    float y = (y0+y1) + (y2+y3);
    ygp[(size_t)t*BB*DINNER] = f2b((y + xp*Dv) * siluf(zg));
    dx = dxn; zg = zgn;
  }
}

// ---------------- fused out-proj (BK=64) + residual + action head + log-prob
__global__ __launch_bounds__(256) void outhead_k(const u16* __restrict__ YGb,
    const u16* __restrict__ WTo, const u16* __restrict__ Xb,
    const u16* __restrict__ WhT, const float* __restrict__ bh,
    const float* __restrict__ lstd, const float* __restrict__ a,
    float* __restrict__ out)
{
  __shared__ u16 SH[(64+256)*72];
  u16* As = SH;
  u16* Bs = SH + 64*72;
  const int tid = threadIdx.x;
  const int wave = tid >> 6, lane = tid & 63;
  const int quad = lane >> 4, l16 = lane & 15;
  const int m0 = blockIdx.x*64;
  const int n0 = wave*64;
  const int srow = tid >> 3, sch = (tid & 7)*8;
  floatx4 acc[4][4];
  #pragma unroll
  for (int r = 0; r < 4; ++r)
    #pragma unroll
    for (int c = 0; c < 4; ++c) acc[r][c] = (floatx4){0.f,0.f,0.f,0.f};

  for (int k0 = 0; k0 < DINNER; k0 += 64) {
    #pragma unroll
    for (int p = 0; p < 2; ++p) {
      int row = srow + p*32;
      *(uint4*)&As[row*72 + sch] = *(const uint4*)&YGb[(size_t)(m0+row)*DINNER + k0 + sch];
    }
    #pragma unroll
    for (int p = 0; p < 8; ++p) {
      int row = srow + p*32;
      *(uint4*)&Bs[row*72 + sch] = *(const uint4*)&WTo[(size_t)row*DINNER + k0 + sch];
    }
    __syncthreads();
    #pragma unroll
    for (int ks = 0; ks < 2; ++ks) {
      bf16x8 af[4], bf[4];
      #pragma unroll
      for (int r = 0; r < 4; ++r)
        af[r] = *(const bf16x8*)&As[(r*16 + l16)*72 + ks*32 + quad*8];
      #pragma unroll
      for (int c = 0; c < 4; ++c)
        bf[c] = *(const bf16x8*)&Bs[(n0 + c*16 + l16)*72 + ks*32 + quad*8];
      #pragma unroll
      for (int r = 0; r < 4; ++r)
        #pragma unroll
        for (int c = 0; c < 4; ++c)
          acc[r][c] = __builtin_amdgcn_mfma_f32_16x16x32_bf16(af[r], bf[c], acc[r][c], 0, 0, 0);
    }
    __syncthreads();
  }
  u16* Xs = SH;                         // [64][264]
  #pragma unroll
  for (int p = 0; p < 8; ++p) {
    int row = p*8 + (tid >> 5);
    int col = (tid & 31)*8;
    *(uint4*)&Xs[row*264 + col] = *(const uint4*)&Xb[(size_t)(m0+row)*256 + col];
  }
  __syncthreads();
  #pragma unroll
  for (int c = 0; c < 4; ++c) {
    int n = n0 + c*16 + l16;
    #pragma unroll
    for (int r = 0; r < 4; ++r) {
      #pragma unroll
      for (int reg = 0; reg < 4; ++reg) {
        int ml = r*16 + quad*4 + reg;
        Xs[ml*264 + n] = f2b(acc[r][c][reg] + b2f(Xs[ml*264 + n]));
      }
    }
  }
  __syncthreads();
  floatx4 mu[2];
  mu[0] = (floatx4){0.f,0.f,0.f,0.f};
  mu[1] = (floatx4){0.f,0.f,0.f,0.f};
  #pragma unroll
  for (int k0 = 0; k0 < DMODEL; k0 += 32) {
    bf16x8 axf = *(const bf16x8*)&Xs[(wave*16 + l16)*264 + k0 + quad*8];
    #pragma unroll
    for (int nt = 0; nt < 2; ++nt) {
      bf16x8 bwf = *(const bf16x8*)(WhT + (size_t)(nt*16 + l16)*DMODEL + k0 + quad*8);
      mu[nt] = __builtin_amdgcn_mfma_f32_16x16x32_bf16(axf, bwf, mu[nt], 0, 0, 0);
    }
  }
  float ls0 = lstd[l16],      els0 = __expf(-ls0), bh0 = bh[l16];
  float ls1 = lstd[16 + l16], els1 = __expf(-ls1), bh1 = bh[16 + l16];
  #pragma unroll
  for (int reg = 0; reg < 4; ++reg) {
    int tok = m0 + wave*16 + quad*4 + reg;
    float m0v = mu[0][reg] + bh0;
    float m1v = mu[1][reg] + bh1;
    float z0 = (a[(size_t)tok*32 + l16]      - m0v) * els0;
    float z1 = (a[(size_t)tok*32 + 16 + l16] - m1v) * els1;
    float t = (-0.5f*z0*z0 - ls0) + (-0.5f*z1*z1 - ls1) - 2.f*0.91893853320467274f;
    t += __shfl_xor(t, 1);
    t += __shfl_xor(t, 2);
    t += __shfl_xor(t, 4);
    t += __shfl_xor(t, 8);
    if (l16 == 0) out[tok] = t;
  }
}

extern "C" void kernel_launch(void* const* d_in, const int* in_sizes, int n_in,
                              void* d_out, int out_size, void* d_ws, size_t ws_size,
                              hipStream_t stream)
{
  const float* s    = (const float*)d_in[0];
  const float* a    = (const float*)d_in[1];
  const float* Wemb = (const float*)d_in[2];
  const float* bemb = (const float*)d_in[3];
  const float* nw   = (const float*)d_in[4];
  const float* Win  = (const float*)d_in[5];
  const float* cw   = (const float*)d_in[6];
  const float* cb   = (const float*)d_in[7];
  const float* Wx   = (const float*)d_in[8];
  const float* Wdt  = (const float*)d_in[9];
  const float* bdt  = (const float*)d_in[10];
  const float* Alog = (const float*)d_in[11];
  const float* Dp   = (const float*)d_in[12];
  const float* Wout = (const float*)d_in[13];
  const float* Wh   = (const float*)d_in[14];
  const float* bh   = (const float*)d_in[15];
  const float* lstd = (const float*)d_in[16];

  // -------- workspace layout (~140 MB)
  u16*   Xb   = (u16*)d_ws;                         // NTOK*256 bf16 (emb resid)
  u16*   XZb  = Xb  + (size_t)NTOK*DMODEL;          // NTOK*1024 bf16 [xp|z]
  u16*   XNb  = XZb + (size_t)NTOK*1024;            // NTOK*256 bf16
  u16*   YGb  = XNb + (size_t)NTOK*DMODEL;          // NTOK*512 bf16
  u16*   WTe  = YGb + (size_t)NTOK*DINNER;          // 256*128
  u16*   WTi  = WTe + 256*128;                      // 1024*256
  u16*   WTo  = WTi + 1024*256;                     // 256*512
  u16*   WxT  = WTo + 256*512;                      // 48*512
  u16*   WhT  = WxT + 48*512;                       // 32*256
  u16*   HENDb= WhT + 32*256;                       // NSEG*8*512*16 bf16
  unsigned* DXb = (unsigned*)(HENDb + (size_t)NSEG*BB*DINNER*16); // NTOK*512 u32
  float* BM   = (float*)(DXb + (size_t)NTOK*DINNER);// NTOK*16 fp32
  float* CM   = BM + (size_t)NTOK*16;               // NTOK*16 fp32
  float* DTR  = CM + (size_t)NTOK*16;               // NTOK*16 fp32
  float* DTS  = DTR + (size_t)NTOK*16;              // NSEG*8*512 fp32
  float* out  = (float*)d_out;

  prep_k        <<<1792,        256, 0, stream>>>(Wemb, Win, Wout, Wx, Wh,
                                                  WTe, WTi, WTo, WxT, WhT);
  embnorm_k     <<<256,         256, 0, stream>>>(s, WTe, bemb, nw, Xb, XNb);
  gemm_mfma<256><<<dim3(128,8), 256, 0, stream>>>(XNb, WTi, XZb, 1024);
  xdblBC_k      <<<256,         256, 0, stream>>>(XZb, cw, cb, WxT, BM, CM, DTR);
  scanA_k       <<<dim3(NSEG,BB,2), 256, 0, stream>>>(DTR, XZb, BM, cw, cb, Wdt, bdt,
                                                      Alog, HENDb, DTS, DXb);
  stitch_k      <<<256,         256, 0, stream>>>(HENDb, DTS, Alog);
  scanC_k       <<<dim3(NSEG,BB,2), 256, 0, stream>>>(DXb, XZb, BM, CM,
                                                      Alog, Dp, HENDb, YGb);
  outhead_k     <<<256,         256, 0, stream>>>(YGb, WTo, Xb, WhT, bh, lstd, a, out);
}

// Round 16
// 244.073 us; speedup vs baseline: 1.0301x; 1.0179x over previous
//
#include <hip/hip_runtime.h>

typedef unsigned short u16;
typedef short bf16x8 __attribute__((ext_vector_type(8)));   // 8 bf16 = 4 VGPR
typedef float floatx4 __attribute__((ext_vector_type(4)));

#define LSEQ 2048
#define BB 8
#define NTOK (LSEQ*BB)        // 16384 tokens, n = l*B + b
#define DMODEL 256
#define DINNER 512
#define NSEG 128
#define SEGLEN 16             // LSEQ / NSEG

__device__ __forceinline__ float siluf(float x){ return x / (1.f + __expf(-x)); }
__device__ __forceinline__ float b2f(u16 x){ return __uint_as_float(((unsigned)x) << 16); }
__device__ __forceinline__ u16 f2b(float f){
  unsigned u = __float_as_uint(f);
  unsigned r = (u + 0x7fffu + ((u >> 16) & 1u)) >> 16;
  return (u16)r;
}

// ---------------- prep: 5 weight transpose/casts, range-switched
__global__ __launch_bounds__(256) void prep_k(
    const float* __restrict__ Wemb, const float* __restrict__ Win,
    const float* __restrict__ Wout, const float* __restrict__ Wx,
    const float* __restrict__ Wh,
    u16* __restrict__ WTe, u16* __restrict__ WTi, u16* __restrict__ WTo,
    u16* __restrict__ WxT, u16* __restrict__ WhT)
{
  int g = blockIdx.x, tid = threadIdx.x;
  if (g < 128) {                        // WTe[n][k], n<256, k<128
    int idx = g*256 + tid; int n = idx >> 7, k = idx & 127;
    WTe[idx] = f2b(Wemb[(size_t)k*256 + n]);
  } else if (g < 1152) {                // WTi[n][k], n<1024, k<256
    int idx = (g-128)*256 + tid; int n = idx >> 8, k = idx & 255;
    WTi[idx] = f2b(Win[(size_t)k*1024 + n]);
  } else if (g < 1664) {                // WTo[n][k], n<256, k<512
    int idx = (g-1152)*256 + tid; int n = idx >> 9, k = idx & 511;
    WTo[idx] = f2b(Wout[(size_t)k*256 + n]);
  } else if (g < 1760) {                // WxT[48][512]
    int idx = (g-1664)*256 + tid; int n = idx >> 9, k = idx & 511;
    WxT[idx] = f2b(Wx[(size_t)k*48 + n]);
  } else {                              // WhT[32][256]
    int idx = (g-1760)*256 + tid; int j = idx >> 8, k = idx & 255;
    WhT[idx] = f2b(Wh[(size_t)k*32 + j]);
  }
}

// ---------------- fused emb GEMM + RMSNorm: block = 64 tokens x full N=256.
__global__ __launch_bounds__(256) void embnorm_k(
    const float* __restrict__ s, const u16* __restrict__ WTe,
    const float* __restrict__ bemb, const float* __restrict__ nw,
    u16* __restrict__ Xb, u16* __restrict__ XNb)
{
  __shared__ u16 SH[64*264];
  __shared__ float ssq[64*4];
  __shared__ float rr[64];
  u16* As = SH;
  u16* Bs = SH + 64*40;
  const int tid = threadIdx.x;
  const int wave = tid >> 6, lane = tid & 63;
  const int quad = lane >> 4, l16 = lane & 15;
  const int m0 = blockIdx.x*64;
  const int wn = wave*64;
  const int srow = tid >> 2, sch = (tid & 3)*8;
  floatx4 acc[4][4];
  #pragma unroll
  for (int r = 0; r < 4; ++r)
    #pragma unroll
    for (int c = 0; c < 4; ++c) acc[r][c] = (floatx4){0.f,0.f,0.f,0.f};

  for (int k0 = 0; k0 < 128; k0 += 32) {
    {
      float4 v0 = *(const float4*)&s[(size_t)(m0+srow)*128 + k0 + sch];
      float4 v1 = *(const float4*)&s[(size_t)(m0+srow)*128 + k0 + sch + 4];
      __align__(16) u16 o[8];
      o[0]=f2b(v0.x); o[1]=f2b(v0.y); o[2]=f2b(v0.z); o[3]=f2b(v0.w);
      o[4]=f2b(v1.x); o[5]=f2b(v1.y); o[6]=f2b(v1.z); o[7]=f2b(v1.w);
      *(uint4*)&As[srow*40 + sch] = *(const uint4*)o;
    }
    #pragma unroll
    for (int p = 0; p < 4; ++p) {
      int row = srow + p*64;
      *(uint4*)&Bs[row*40 + sch] = *(const uint4*)&WTe[(size_t)row*128 + k0 + sch];
    }
    __syncthreads();
    bf16x8 af[4], bf[4];
    #pragma unroll
    for (int r = 0; r < 4; ++r) af[r] = *(const bf16x8*)&As[(r*16 + l16)*40 + quad*8];
    #pragma unroll
    for (int c = 0; c < 4; ++c) bf[c] = *(const bf16x8*)&Bs[(wn + c*16 + l16)*40 + quad*8];
    #pragma unroll
    for (int r = 0; r < 4; ++r)
      #pragma unroll
      for (int c = 0; c < 4; ++c)
        acc[r][c] = __builtin_amdgcn_mfma_f32_16x16x32_bf16(af[r], bf[c], acc[r][c], 0, 0, 0);
    __syncthreads();
  }
  u16* Xs = SH;                         // [64][264]
  #pragma unroll
  for (int c = 0; c < 4; ++c) {
    int n = wn + c*16 + l16;
    float bv = bemb[n];
    #pragma unroll
    for (int r = 0; r < 4; ++r)
      #pragma unroll
      for (int reg = 0; reg < 4; ++reg) {
        int ml = r*16 + quad*4 + reg;
        Xs[ml*264 + n] = f2b(acc[r][c][reg] + bv);
      }
  }
  __syncthreads();
  #pragma unroll
  for (int p = 0; p < 8; ++p) {
    int row = p*8 + (tid >> 5);
    int col = (tid & 31)*8;
    *(uint4*)&Xb[(size_t)(m0+row)*256 + col] = *(const uint4*)&Xs[row*264 + col];
  }
  const int tk = tid >> 2, q = tid & 3;
  float ss = 0.f;
  #pragma unroll
  for (int j = 0; j < 8; ++j) {
    uint4 v = *(const uint4*)&Xs[tk*264 + q*64 + j*8];
    const u16* u = (const u16*)&v;
    #pragma unroll
    for (int i = 0; i < 8; ++i) { float x = b2f(u[i]); ss += x*x; }
  }
  ssq[tk*4 + q] = ss;
  __syncthreads();
  if (q == 0)
    rr[tk] = rsqrtf((ssq[tk*4]+ssq[tk*4+1]+ssq[tk*4+2]+ssq[tk*4+3])*(1.f/DMODEL) + 1e-5f);
  __syncthreads();
  float r = rr[tk];
  #pragma unroll
  for (int j = 0; j < 8; ++j) {
    int idx = q*64 + j*8;
    uint4 v = *(const uint4*)&Xs[tk*264 + idx];
    const u16* u = (const u16*)&v;
    float4 w0 = *(const float4*)&nw[idx];
    float4 w1 = *(const float4*)&nw[idx+4];
    __align__(16) u16 o[8];
    o[0]=f2b(b2f(u[0])*r*w0.x); o[1]=f2b(b2f(u[1])*r*w0.y);
    o[2]=f2b(b2f(u[2])*r*w0.z); o[3]=f2b(b2f(u[3])*r*w0.w);
    o[4]=f2b(b2f(u[4])*r*w1.x); o[5]=f2b(b2f(u[5])*r*w1.y);
    o[6]=f2b(b2f(u[6])*r*w1.z); o[7]=f2b(b2f(u[7])*r*w1.w);
    *(uint4*)&XNb[(size_t)(m0+tk)*256 + idx] = *(const uint4*)o;
  }
}

// ---------------- LDS-staged bf16 MFMA GEMM (in-proj), BK=64: C = A @ W, bf16 out
template<int K>
__global__ __launch_bounds__(256) void gemm_mfma(
    const u16* __restrict__ Ab, const u16* __restrict__ WT,
    u16* __restrict__ Cv, int N)
{
  __shared__ u16 SH[2*128*72];
  u16* As = SH;
  u16* Bs = SH + 128*72;
  const int tid = threadIdx.x;
  const int wave = tid >> 6, lane = tid & 63;
  const int quad = lane >> 4, l16 = lane & 15;
  const int bm0 = blockIdx.x*128, bn0 = blockIdx.y*128;
  const int wm = (wave & 1)*64, wn = (wave >> 1)*64;
  const int srow = tid >> 3, sch = (tid & 7)*8;
  floatx4 acc[4][4];
  #pragma unroll
  for (int r = 0; r < 4; ++r)
    #pragma unroll
    for (int c = 0; c < 4; ++c) acc[r][c] = (floatx4){0.f,0.f,0.f,0.f};

  for (int k0 = 0; k0 < K; k0 += 64) {
    #pragma unroll
    for (int p = 0; p < 4; ++p) {
      int row = srow + p*32;
      *(uint4*)&As[row*72 + sch] = *(const uint4*)&Ab[(size_t)(bm0+row)*K + k0 + sch];
      *(uint4*)&Bs[row*72 + sch] = *(const uint4*)&WT[(size_t)(bn0+row)*K + k0 + sch];
    }
    __syncthreads();
    #pragma unroll
    for (int ks = 0; ks < 2; ++ks) {
      bf16x8 af[4], bf[4];
      #pragma unroll
      for (int r = 0; r < 4; ++r)
        af[r] = *(const bf16x8*)&As[(wm + r*16 + l16)*72 + ks*32 + quad*8];
      #pragma unroll
      for (int c = 0; c < 4; ++c)
        bf[c] = *(const bf16x8*)&Bs[(wn + c*16 + l16)*72 + ks*32 + quad*8];
      #pragma unroll
      for (int r = 0; r < 4; ++r)
        #pragma unroll
        for (int c = 0; c < 4; ++c)
          acc[r][c] = __builtin_amdgcn_mfma_f32_16x16x32_bf16(af[r], bf[c], acc[r][c], 0, 0, 0);
    }
    __syncthreads();
  }
  u16* Cs = SH;                         // [128][136]
  #pragma unroll
  for (int c = 0; c < 4; ++c) {
    int nl = wn + c*16 + l16;
    #pragma unroll
    for (int r = 0; r < 4; ++r)
      #pragma unroll
      for (int reg = 0; reg < 4; ++reg) {
        int ml = wm + r*16 + quad*4 + reg;
        Cs[ml*136 + nl] = f2b(acc[r][c][reg]);
      }
  }
  __syncthreads();
  #pragma unroll
  for (int p = 0; p < 8; ++p) {
    int row = p*16 + (tid >> 4);
    int col = (tid & 15)*8;
    uint4 v = *(const uint4*)&Cs[row*136 + col];
    *(uint4*)&Cv[(size_t)(bm0+row)*N + bn0 + col] = v;
  }
}

// ---------------- x_dbl GEMM1 with fused causal conv+SiLU in the staging phase.
__global__ __launch_bounds__(256) void xdblBC_k(const u16* __restrict__ XZb,
    const float* __restrict__ cw, const float* __restrict__ cb,
    const u16* __restrict__ WxT,
    float* __restrict__ BM, float* __restrict__ CM, float* __restrict__ DTR)
{
  __shared__ u16 As[64*40];
  __shared__ u16 Ws[48*40];
  __shared__ float CWs[512*4];
  __shared__ float CBs[512];
  const int tid = threadIdx.x;
  const int wave = tid >> 6, lane = tid & 63;
  const int quad = lane >> 4, l16 = lane & 15;
  const int m0 = blockIdx.x*64;
  const int srow = tid >> 2, sch = (tid & 3)*8;
  const int n = m0 + srow;
  for (int e = tid; e < 2048; e += 256) CWs[e] = cw[e];
  for (int e = tid; e < 512;  e += 256) CBs[e] = cb[e];
  floatx4 acc[3];
  #pragma unroll
  for (int j = 0; j < 3; ++j) acc[j] = (floatx4){0.f,0.f,0.f,0.f};
  __syncthreads();
  const bf16x8 z8 = {0,0,0,0,0,0,0,0};
  for (int k0 = 0; k0 < DINNER; k0 += 32) {
    bf16x8 t3 = *(const bf16x8*)&XZb[(size_t)n*1024 + k0 + sch];
    bf16x8 t2 = z8, t1 = z8, t0v = z8;
    if (n >= 8)  t2  = *(const bf16x8*)&XZb[(size_t)(n-8)*1024  + k0 + sch];
    if (n >= 16) t1  = *(const bf16x8*)&XZb[(size_t)(n-16)*1024 + k0 + sch];
    if (n >= 24) t0v = *(const bf16x8*)&XZb[(size_t)(n-24)*1024 + k0 + sch];
    __align__(16) u16 outa[8];
    #pragma unroll
    for (int j = 0; j < 8; ++j) {
      int c = k0 + sch + j;
      float4 wv = *(const float4*)&CWs[c*4];
      float xc = CBs[c] + wv.x*b2f((u16)t0v[j]) + wv.y*b2f((u16)t1[j])
               + wv.z*b2f((u16)t2[j]) + wv.w*b2f((u16)t3[j]);
      outa[j] = f2b(siluf(xc));
    }
    *(uint4*)&As[srow*40 + sch] = *(const uint4*)outa;
    if (tid < 192) {
      int wr = tid >> 2;
      *(uint4*)&Ws[wr*40 + sch] = *(const uint4*)&WxT[(size_t)wr*512 + k0 + sch];
    }
    __syncthreads();
    bf16x8 af = *(const bf16x8*)&As[(wave*16 + l16)*40 + quad*8];
    #pragma unroll
    for (int j = 0; j < 3; ++j) {
      bf16x8 bf = *(const bf16x8*)&Ws[(j*16 + l16)*40 + quad*8];
      acc[j] = __builtin_amdgcn_mfma_f32_16x16x32_bf16(af, bf, acc[j], 0, 0, 0);
    }
    __syncthreads();
  }
  const int tok0 = m0 + wave*16;
  #pragma unroll
  for (int reg = 0; reg < 4; ++reg) {
    size_t t = (size_t)(tok0 + quad*4 + reg);
    BM[t*16 + l16]  = acc[1][reg];
    CM[t*16 + l16]  = acc[2][reg];
    DTR[t*16 + l16] = acc[0][reg];
  }
}

// ---------------- scan phase A: rolling conv + dt projection, software-pipelined
// uniform row loads (B, dtr). Stores h_end (bf16), sum(dt), packed {dt,xp}.
__global__ __launch_bounds__(256) void scanA_k(const float* __restrict__ DTR,
    const u16* __restrict__ XZb, const float* __restrict__ BM,
    const float* __restrict__ cw, const float* __restrict__ cb,
    const float* __restrict__ Wdt, const float* __restrict__ bdt,
    const float* __restrict__ Alog, u16* __restrict__ HENDb, float* __restrict__ DTS,
    unsigned* __restrict__ DXb)
{
  const int tid = threadIdx.x;
  const int seg = blockIdx.x, b = blockIdx.y, half = blockIdx.z;
  const int c = half*256 + tid;
  const int t0 = seg*SEGLEN;
  float As[16];
  #pragma unroll
  for (int s = 0; s < 16; ++s) As[s] = -__expf(Alog[c*16+s]);
  bool uni = true;
  #pragma unroll
  for (int s = 1; s < 16; ++s)
    uni = uni && (fabsf(As[s] - As[0]*(float)(s+1)) <= 1e-4f*(float)(s+1));
  float wdt[16];
  #pragma unroll
  for (int r = 0; r < 16; ++r) wdt[r] = Wdt[r*DINNER + c];
  const float bd = bdt[c];
  const float4 cwv = *(const float4*)&cw[c*4];
  const float cbv = cb[c];
  float h[16];
  #pragma unroll
  for (int s = 0; s < 16; ++s) h[s] = 0.f;
  float dts = 0.f;
  const size_t base = (size_t)t0*BB + b;
  const u16* xzp = XZb + base*1024 + c;
  float w0 = (t0 >= 3) ? b2f(xzp[-(size_t)3*BB*1024]) : 0.f;
  float w1 = (t0 >= 2) ? b2f(xzp[-(size_t)2*BB*1024]) : 0.f;
  float w2 = (t0 >= 1) ? b2f(xzp[-(size_t)1*BB*1024]) : 0.f;
  float xz = b2f(xzp[0]);
  // pipelined row state
  size_t nb16 = base*16;
  float4 b0 = *(const float4*)&BM[nb16+0],  b1 = *(const float4*)&BM[nb16+4];
  float4 b2 = *(const float4*)&BM[nb16+8],  b3 = *(const float4*)&BM[nb16+12];
  float4 d0 = *(const float4*)&DTR[nb16+0], d1 = *(const float4*)&DTR[nb16+4];
  float4 d2 = *(const float4*)&DTR[nb16+8], d3 = *(const float4*)&DTR[nb16+12];
  for (int t = 0; t < SEGLEN; ++t) {
    float xzn = 0.f;
    float4 nb0, nb1, nb2, nb3, nd0, nd1, nd2, nd3;
    if (t+1 < SEGLEN) {
      xzn = b2f(xzp[(size_t)(t+1)*BB*1024]);
      size_t nn = nb16 + (size_t)(t+1)*BB*16;
      nb0 = *(const float4*)&BM[nn+0];  nb1 = *(const float4*)&BM[nn+4];
      nb2 = *(const float4*)&BM[nn+8];  nb3 = *(const float4*)&BM[nn+12];
      nd0 = *(const float4*)&DTR[nn+0]; nd1 = *(const float4*)&DTR[nn+4];
      nd2 = *(const float4*)&DTR[nn+8]; nd3 = *(const float4*)&DTR[nn+12];
    }
    float dsum = bd;
    dsum = fmaf(d0.x,wdt[0],dsum);  dsum = fmaf(d0.y,wdt[1],dsum);
    dsum = fmaf(d0.z,wdt[2],dsum);  dsum = fmaf(d0.w,wdt[3],dsum);
    dsum = fmaf(d1.x,wdt[4],dsum);  dsum = fmaf(d1.y,wdt[5],dsum);
    dsum = fmaf(d1.z,wdt[6],dsum);  dsum = fmaf(d1.w,wdt[7],dsum);
    dsum = fmaf(d2.x,wdt[8],dsum);  dsum = fmaf(d2.y,wdt[9],dsum);
    dsum = fmaf(d2.z,wdt[10],dsum); dsum = fmaf(d2.w,wdt[11],dsum);
    dsum = fmaf(d3.x,wdt[12],dsum); dsum = fmaf(d3.y,wdt[13],dsum);
    dsum = fmaf(d3.z,wdt[14],dsum); dsum = fmaf(d3.w,wdt[15],dsum);
    float dt = (dsum > 20.f) ? dsum : __logf(1.f + __expf(dsum));
    float xp = siluf(cbv + cwv.x*w0 + cwv.y*w1 + cwv.z*w2 + cwv.w*xz);
    w0 = w1; w1 = w2; w2 = xz;
    dts += dt;
    DXb[(((size_t)(t0+t)*BB + b)*DINNER + c)] = ((unsigned)f2b(xp) << 16) | f2b(dt);
    float dtx = dt * xp;
    const float bv[16] = {b0.x,b0.y,b0.z,b0.w, b1.x,b1.y,b1.z,b1.w,
                          b2.x,b2.y,b2.z,b2.w, b3.x,b3.y,b3.z,b3.w};
    float dA[16];
    if (uni) {
      float p = __expf(dt*As[0]);
      float p2 = p*p, p4 = p2*p2, p8 = p4*p4;
      dA[0]=p;      dA[1]=p2;     dA[2]=p2*p;   dA[3]=p4;
      dA[4]=p4*p;   dA[5]=p4*p2;  dA[6]=p4*p2*p;dA[7]=p8;
      dA[8]=p8*p;   dA[9]=p8*p2;  dA[10]=p8*p2*p; dA[11]=p8*p4;
      dA[12]=p8*p4*p; dA[13]=p8*p4*p2; dA[14]=p8*p4*p2*p; dA[15]=p8*p8;
    } else {
      #pragma unroll
      for (int s = 0; s < 16; ++s) dA[s] = __expf(dt*As[s]);
    }
    #pragma unroll
    for (int s = 0; s < 16; ++s)
      h[s] = fmaf(dA[s], h[s], dtx*bv[s]);
    xz = xzn;
    b0=nb0; b1=nb1; b2=nb2; b3=nb3;
    d0=nd0; d1=nd1; d2=nd2; d3=nd3;
  }
  u16* hp = &HENDb[(((size_t)seg*BB + b)*DINNER + c)*16];
  #pragma unroll
  for (int q = 0; q < 2; ++q) {
    ushort4 v0, v1;
    v0.x = f2b(h[q*8+0]); v0.y = f2b(h[q*8+1]); v0.z = f2b(h[q*8+2]); v0.w = f2b(h[q*8+3]);
    v1.x = f2b(h[q*8+4]); v1.y = f2b(h[q*8+5]); v1.z = f2b(h[q*8+6]); v1.w = f2b(h[q*8+7]);
    *(ushort4*)&hp[q*8]     = v0;
    *(ushort4*)&hp[q*8 + 4] = v1;
  }
  DTS[((size_t)seg*BB + b)*DINNER + c] = dts;
}

// ---------------- stitch: sequential over NSEG segments, in-place HENDb -> h0
__global__ __launch_bounds__(256) void stitch_k(u16* __restrict__ HENDb,
    const float* __restrict__ DTS, const float* __restrict__ Alog)
{
  int g = blockIdx.x*256 + threadIdx.x;
  int b = g >> 13;
  int rem = g & 8191;          // c*16+s
  int cidx = rem >> 4;
  float A = -__expf(Alog[rem]);
  float h0 = 0.f;
  for (int k = 0; k < NSEG; ++k) {
    size_t idx = (((size_t)k*BB + b) << 13) + rem;
    float hend = b2f(HENDb[idx]);
    HENDb[idx] = f2b(h0);
    float dts = DTS[((size_t)k*BB + b)*DINNER + cidx];
    h0 = fmaf(__expf(dts*A), h0, hend);
  }
}

// ---------------- scan phase C: packed {dt,xp}; software-pipelined B/C rows;
// full scan with h0, gate, bf16 out.
__global__ __launch_bounds__(256) void scanC_k(const unsigned* __restrict__ DXb,
    const u16* __restrict__ XZb, const float* __restrict__ BM, const float* __restrict__ CM,
    const float* __restrict__ Alog, const float* __restrict__ Dp,
    const u16* __restrict__ H0b, u16* __restrict__ YGb)
{
  const int tid = threadIdx.x;
  const int seg = blockIdx.x, b = blockIdx.y, half = blockIdx.z;
  const int c = half*256 + tid;
  const int t0 = seg*SEGLEN;
  float As[16];
  #pragma unroll
  for (int s = 0; s < 16; ++s) As[s] = -__expf(Alog[c*16+s]);
  bool uni = true;
  #pragma unroll
  for (int s = 1; s < 16; ++s)
    uni = uni && (fabsf(As[s] - As[0]*(float)(s+1)) <= 1e-4f*(float)(s+1));
  float h[16];
  const u16* hp = &H0b[(((size_t)seg*BB + b)*DINNER + c)*16];
  #pragma unroll
  for (int q = 0; q < 4; ++q) {
    ushort4 hv = *(const ushort4*)&hp[q*4];
    h[q*4+0]=b2f(hv.x); h[q*4+1]=b2f(hv.y); h[q*4+2]=b2f(hv.z); h[q*4+3]=b2f(hv.w);
  }
  const float Dv = Dp[c];
  const size_t base = (size_t)t0*BB + b;
  const unsigned* dxp = DXb + base*DINNER + c;
  const u16* zp  = XZb + base*1024 + DINNER + c;
  u16*       ygp = YGb + base*DINNER + c;
  unsigned dx = dxp[0];
  float zg = b2f(zp[0]);
  size_t nb16 = base*16;
  float4 b0 = *(const float4*)&BM[nb16+0],  b1 = *(const float4*)&BM[nb16+4];
  float4 b2 = *(const float4*)&BM[nb16+8],  b3 = *(const float4*)&BM[nb16+12];
  float4 c0 = *(const float4*)&CM[nb16+0],  c1 = *(const float4*)&CM[nb16+4];
  float4 c2 = *(const float4*)&CM[nb16+8],  c3 = *(const float4*)&CM[nb16+12];
  for (int t = 0; t < SEGLEN; ++t) {
    unsigned dxn = 0; float zgn = 0.f;
    float4 nb0, nb1, nb2, nb3, nc0, nc1, nc2, nc3;
    if (t+1 < SEGLEN) {
      dxn = dxp[(size_t)(t+1)*BB*DINNER];
      zgn = b2f(zp[(size_t)(t+1)*BB*1024]);
      size_t nn = nb16 + (size_t)(t+1)*BB*16;
      nb0 = *(const float4*)&BM[nn+0]; nb1 = *(const float4*)&BM[nn+4];
      nb2 = *(const float4*)&BM[nn+8]; nb3 = *(const float4*)&BM[nn+12];
      nc0 = *(const float4*)&CM[nn+0]; nc1 = *(const float4*)&CM[nn+4];
      nc2 = *(const float4*)&CM[nn+8]; nc3 = *(const float4*)&CM[nn+12];
    }
    float dt = __uint_as_float(dx << 16);
    float xp = __uint_as_float(dx & 0xffff0000u);
    const float bvv[16] = {b0.x,b0.y,b0.z,b0.w, b1.x,b1.y,b1.z,b1.w,
                           b2.x,b2.y,b2.z,b2.w, b3.x,b3.y,b3.z,b3.w};
    const float cvv[16] = {c0.x,c0.y,c0.z,c0.w, c1.x,c1.y,c1.z,c1.w,
                           c2.x,c2.y,c2.z,c2.w, c3.x,c3.y,c3.z,c3.w};
    float dtx = dt * xp;
    float dA[16];
    if (uni) {
      float p = __expf(dt*As[0]);
      float p2 = p*p, p4 = p2*p2, p8 = p4*p4;
      dA[0]=p;      dA[1]=p2;     dA[2]=p2*p;   dA[3]=p4;
      dA[4]=p4*p;   dA[5]=p4*p2;  dA[6]=p4*p2*p;dA[7]=p8;
      dA[8]=p8*p;   dA[9]=p8*p2;  dA[10]=p8*p2*p; dA[11]=p8*p4;
      dA[12]=p8*p4*p; dA[13]=p8*p4*p2; dA[14]=p8*p4*p2*p; dA[15]=p8*p8;
    } else {
      #pragma unroll
      for (int s = 0; s < 16; ++s) dA[s] = __expf(dt*As[s]);
    }
    float y0 = 0.f, y1 = 0.f, y2 = 0.f, y3 = 0.f;
    #pragma unroll
    for (int q = 0; q < 4; ++q) {
      h[q*4+0] = fmaf(dA[q*4+0], h[q*4+0], dtx*bvv[q*4+0]);
      h[q*4+1] = fmaf(dA[q*4+1], h[q*4+1], dtx*bvv[q*4+1]);
      h[q*4+2] = fmaf(dA[q*4+2], h[q*4+2], dtx*bvv[q*4+2]);
      h[q*4+3] = fmaf(dA[q*4+3], h[q*4+3], dtx*bvv[q*4+3]);
      y0 = fmaf(h[q*4+0], cvv[q*4+0], y0);
      y1 = fmaf(h[q*4+1], cvv[q*4+1], y1);
      y2 = fmaf(h[q*4+2], cvv[q*4+2], y2);
      y3 = fmaf(h[q*4+3], cvv[q*4+3], y3);
    }
    float y = (y0+y1) + (y2+y3);
    ygp[(size_t)t*BB*DINNER] = f2b((y + xp*Dv) * siluf(zg));
    dx = dxn; zg = zgn;
    b0=nb0; b1=nb1; b2=nb2; b3=nb3;
    c0=nc0; c1=nc1; c2=nc2; c3=nc3;
  }
}

// ---------------- fused out-proj (BK=64) + residual + action head + log-prob
__global__ __launch_bounds__(256) void outhead_k(const u16* __restrict__ YGb,
    const u16* __restrict__ WTo, const u16* __restrict__ Xb,
    const u16* __restrict__ WhT, const float* __restrict__ bh,
    const float* __restrict__ lstd, const float* __restrict__ a,
    float* __restrict__ out)
{
  __shared__ u16 SH[(64+256)*72];
  u16* As = SH;
  u16* Bs = SH + 64*72;
  const int tid = threadIdx.x;
  const int wave = tid >> 6, lane = tid & 63;
  const int quad = lane >> 4, l16 = lane & 15;
  const int m0 = blockIdx.x*64;
  const int n0 = wave*64;
  const int srow = tid >> 3, sch = (tid & 7)*8;
  floatx4 acc[4][4];
  #pragma unroll
  for (int r = 0; r < 4; ++r)
    #pragma unroll
    for (int c = 0; c < 4; ++c) acc[r][c] = (floatx4){0.f,0.f,0.f,0.f};

  for (int k0 = 0; k0 < DINNER; k0 += 64) {
    #pragma unroll
    for (int p = 0; p < 2; ++p) {
      int row = srow + p*32;
      *(uint4*)&As[row*72 + sch] = *(const uint4*)&YGb[(size_t)(m0+row)*DINNER + k0 + sch];
    }
    #pragma unroll
    for (int p = 0; p < 8; ++p) {
      int row = srow + p*32;
      *(uint4*)&Bs[row*72 + sch] = *(const uint4*)&WTo[(size_t)row*DINNER + k0 + sch];
    }
    __syncthreads();
    #pragma unroll
    for (int ks = 0; ks < 2; ++ks) {
      bf16x8 af[4], bf[4];
      #pragma unroll
      for (int r = 0; r < 4; ++r)
        af[r] = *(const bf16x8*)&As[(r*16 + l16)*72 + ks*32 + quad*8];
      #pragma unroll
      for (int c = 0; c < 4; ++c)
        bf[c] = *(const bf16x8*)&Bs[(n0 + c*16 + l16)*72 + ks*32 + quad*8];
      #pragma unroll
      for (int r = 0; r < 4; ++r)
        #pragma unroll
        for (int c = 0; c < 4; ++c)
          acc[r][c] = __builtin_amdgcn_mfma_f32_16x16x32_bf16(af[r], bf[c], acc[r][c], 0, 0, 0);
    }
    __syncthreads();
  }
  u16* Xs = SH;                         // [64][264]
  #pragma unroll
  for (int p = 0; p < 8; ++p) {
    int row = p*8 + (tid >> 5);
    int col = (tid & 31)*8;
    *(uint4*)&Xs[row*264 + col] = *(const uint4*)&Xb[(size_t)(m0+row)*256 + col];
  }
  __syncthreads();
  #pragma unroll
  for (int c = 0; c < 4; ++c) {
    int n = n0 + c*16 + l16;
    #pragma unroll
    for (int r = 0; r < 4; ++r) {
      #pragma unroll
      for (int reg = 0; reg < 4; ++reg) {
        int ml = r*16 + quad*4 + reg;
        Xs[ml*264 + n] = f2b(acc[r][c][reg] + b2f(Xs[ml*264 + n]));
      }
    }
  }
  __syncthreads();
  floatx4 mu[2];
  mu[0] = (floatx4){0.f,0.f,0.f,0.f};
  mu[1] = (floatx4){0.f,0.f,0.f,0.f};
  #pragma unroll
  for (int k0 = 0; k0 < DMODEL; k0 += 32) {
    bf16x8 axf = *(const bf16x8*)&Xs[(wave*16 + l16)*264 + k0 + quad*8];
    #pragma unroll
    for (int nt = 0; nt < 2; ++nt) {
      bf16x8 bwf = *(const bf16x8*)(WhT + (size_t)(nt*16 + l16)*DMODEL + k0 + quad*8);
      mu[nt] = __builtin_amdgcn_mfma_f32_16x16x32_bf16(axf, bwf, mu[nt], 0, 0, 0);
    }
  }
  float ls0 = lstd[l16],      els0 = __expf(-ls0), bh0 = bh[l16];
  float ls1 = lstd[16 + l16], els1 = __expf(-ls1), bh1 = bh[16 + l16];
  #pragma unroll
  for (int reg = 0; reg < 4; ++reg) {
    int tok = m0 + wave*16 + quad*4 + reg;
    float m0v = mu[0][reg] + bh0;
    float m1v = mu[1][reg] + bh1;
    float z0 = (a[(size_t)tok*32 + l16]      - m0v) * els0;
    float z1 = (a[(size_t)tok*32 + 16 + l16] - m1v) * els1;
    float t = (-0.5f*z0*z0 - ls0) + (-0.5f*z1*z1 - ls1) - 2.f*0.91893853320467274f;
    t += __shfl_xor(t, 1);
    t += __shfl_xor(t, 2);
    t += __shfl_xor(t, 4);
    t += __shfl_xor(t, 8);
    if (l16 == 0) out[tok] = t;
  }
}

extern "C" void kernel_launch(void* const* d_in, const int* in_sizes, int n_in,
                              void* d_out, int out_size, void* d_ws, size_t ws_size,
                              hipStream_t stream)
{
  const float* s    = (const float*)d_in[0];
  const float* a    = (const float*)d_in[1];
  const float* Wemb = (const float*)d_in[2];
  const float* bemb = (const float*)d_in[3];
  const float* nw   = (const float*)d_in[4];
  const float* Win  = (const float*)d_in[5];
  const float* cw   = (const float*)d_in[6];
  const float* cb   = (const float*)d_in[7];
  const float* Wx   = (const float*)d_in[8];
  const float* Wdt  = (const float*)d_in[9];
  const float* bdt  = (const float*)d_in[10];
  const float* Alog = (const float*)d_in[11];
  const float* Dp   = (const float*)d_in[12];
  const float* Wout = (const float*)d_in[13];
  const float* Wh   = (const float*)d_in[14];
  const float* bh   = (const float*)d_in[15];
  const float* lstd = (const float*)d_in[16];

  // -------- workspace layout (~140 MB)
  u16*   Xb   = (u16*)d_ws;                         // NTOK*256 bf16 (emb resid)
  u16*   XZb  = Xb  + (size_t)NTOK*DMODEL;          // NTOK*1024 bf16 [xp|z]
  u16*   XNb  = XZb + (size_t)NTOK*1024;            // NTOK*256 bf16
  u16*   YGb  = XNb + (size_t)NTOK*DMODEL;          // NTOK*512 bf16
  u16*   WTe  = YGb + (size_t)NTOK*DINNER;          // 256*128
  u16*   WTi  = WTe + 256*128;                      // 1024*256
  u16*   WTo  = WTi + 1024*256;                     // 256*512
  u16*   WxT  = WTo + 256*512;                      // 48*512
  u16*   WhT  = WxT + 48*512;                       // 32*256
  u16*   HENDb= WhT + 32*256;                       // NSEG*8*512*16 bf16
  unsigned* DXb = (unsigned*)(HENDb + (size_t)NSEG*BB*DINNER*16); // NTOK*512 u32
  float* BM   = (float*)(DXb + (size_t)NTOK*DINNER);// NTOK*16 fp32
  float* CM   = BM + (size_t)NTOK*16;               // NTOK*16 fp32
  float* DTR  = CM + (size_t)NTOK*16;               // NTOK*16 fp32
  float* DTS  = DTR + (size_t)NTOK*16;              // NSEG*8*512 fp32
  float* out  = (float*)d_out;

  prep_k        <<<1792,        256, 0, stream>>>(Wemb, Win, Wout, Wx, Wh,
                                                  WTe, WTi, WTo, WxT, WhT);
  embnorm_k     <<<256,         256, 0, stream>>>(s, WTe, bemb, nw, Xb, XNb);
  gemm_mfma<256><<<dim3(128,8), 256, 0, stream>>>(XNb, WTi, XZb, 1024);
  xdblBC_k      <<<256,         256, 0, stream>>>(XZb, cw, cb, WxT, BM, CM, DTR);
  scanA_k       <<<dim3(NSEG,BB,2), 256, 0, stream>>>(DTR, XZb, BM, cw, cb, Wdt, bdt,
                                                      Alog, HENDb, DTS, DXb);
  stitch_k      <<<256,         256, 0, stream>>>(HENDb, DTS, Alog);
  scanC_k       <<<dim3(NSEG,BB,2), 256, 0, stream>>>(DXb, XZb, BM, CM,
                                                      Alog, Dp, HENDb, YGb);
  outhead_k     <<<256,         256, 0, stream>>>(YGb, WTo, Xb, WhT, bh, lstd, a, out);
}